// Round 13
// baseline (256.918 us; speedup 1.0000x reference)
//
#include <hip/hip_runtime.h>
#include <hip/hip_cooperative_groups.h>

namespace cg = cooperative_groups;

// Problem constants (fixed by the reference):
//   B=128 graphs, n=64 nodes/graph, E=65536 edges, K=16, D=64
#define EF      524288
#define NEDGE   65536
#define KDIM    16
#define DDIM    64
#define TPW     2      // 32-row tiles per wave in pv_gemm
#define PVBLK   (EF / (32 * TPW) / 4)   // 2048 logical pv blocks (4 waves each)
#define GRID    512    // cooperative grid: 2 blocks/CU x 256 CU (large margin)

typedef float vfloat4 __attribute__((ext_vector_type(4)));
typedef short bf16x8  __attribute__((ext_vector_type(8)));
typedef float f32x16  __attribute__((ext_vector_type(16)));

__device__ __forceinline__ short f2bf(float f) {   // f32 -> bf16, RNE
    unsigned u = __float_as_uint(f);
    return (short)((u + 0x7FFFu + ((u >> 16) & 1u)) >> 16);
}

__device__ __forceinline__ long edge_slot(const int* ei, int e) {
    int r = ei[e];
    int c = ei[NEDGE + e];
    return ((long)(r >> 6) << 12) + ((long)(r & 63) << 6) + (long)(c & 63);
}

// ---------------------------------------------------------------------------
// Fused cooperative kernel, NO LDS (direct MFMA-layout stores; R11 showed the
// LDS transpose is perf-neutral and it was the occupancy risk for coop launch).
// P1 fill_idx + zero_cnt | sync | P2 count_edges + pv_gemm | sync | P3 scatter
// ---------------------------------------------------------------------------
__global__ __launch_bounds__(256, 4) void fused_all(const float* __restrict__ pv,
                                                    const float* __restrict__ W,
                                                    const float* __restrict__ ea,
                                                    const int*   __restrict__ ei,
                                                    float* __restrict__ out,
                                                    float* __restrict__ outv,
                                                    unsigned* __restrict__ cnt) {
    cg::grid_group grid = cg::this_grid();
    int bid = blockIdx.x;
    int tid = threadIdx.x;
    int gid = bid * 256 + tid;               // [0, 131072) exactly with GRID=512

    // ---------------- P1: zero cnt + fill full_edge_index ----------------
    {
        reinterpret_cast<uint4*>(cnt)[gid] = make_uint4(0, 0, 0, 0);  // 2 MB total
        int j0 = gid << 2;
        vfloat4 rv, cv;
#pragma unroll
        for (int i = 0; i < 4; ++i) {
            int j = j0 + i;
            int g = j >> 12;
            int rem = j & 4095;
            rv[i] = (float)((g << 6) + (rem >> 6));
            cv[i] = (float)((g << 6) + (rem & 63));
        }
        __builtin_nontemporal_store(rv, reinterpret_cast<vfloat4*>(out + j0));
        __builtin_nontemporal_store(cv, reinterpret_cast<vfloat4*>(out + EF + j0));
    }
    __threadfence();
    grid.sync();

    // ---------------- P2: count edges + pv_gemm (MFMA) ----------------
    if (gid < NEDGE) atomicAdd(&cnt[edge_slot(ei, gid)], 1u);

    {
        int wv = tid >> 6;
        int l  = tid & 63;
        int n  = l & 31;
        int kh = l >> 5;

        const float4* wp0 = reinterpret_cast<const float4*>(W + n * KDIM + kh * 8);
        const float4* wp1 = reinterpret_cast<const float4*>(W + (32 + n) * KDIM + kh * 8);
        float4 w0a = wp0[0], w0b = wp0[1], w1a = wp1[0], w1b = wp1[1];
        bf16x8 xa0, xa1;
        xa0[0]=f2bf(w0a.x); xa0[1]=f2bf(w0a.y); xa0[2]=f2bf(w0a.z); xa0[3]=f2bf(w0a.w);
        xa0[4]=f2bf(w0b.x); xa0[5]=f2bf(w0b.y); xa0[6]=f2bf(w0b.z); xa0[7]=f2bf(w0b.w);
        xa1[0]=f2bf(w1a.x); xa1[1]=f2bf(w1a.y); xa1[2]=f2bf(w1a.z); xa1[3]=f2bf(w1a.w);
        xa1[4]=f2bf(w1b.x); xa1[5]=f2bf(w1b.y); xa1[6]=f2bf(w1b.z); xa1[7]=f2bf(w1b.w);

        for (int lb = bid; lb < PVBLK; lb += GRID) {
            long j0 = ((long)lb * 4 + wv) * (32 * TPW);
#pragma unroll
            for (int t = 0; t < TPW; ++t) {
                long jt = j0 + t * 32;
                const float4* bp = reinterpret_cast<const float4*>(pv + (jt + n) * KDIM + kh * 8);
                float4 ba = bp[0], bb = bp[1];
                bf16x8 yf;
                yf[0]=f2bf(ba.x); yf[1]=f2bf(ba.y); yf[2]=f2bf(ba.z); yf[3]=f2bf(ba.w);
                yf[4]=f2bf(bb.x); yf[5]=f2bf(bb.y); yf[6]=f2bf(bb.z); yf[7]=f2bf(bb.w);

                f32x16 acc0 = {0,0,0,0, 0,0,0,0, 0,0,0,0, 0,0,0,0};
                f32x16 acc1 = {0,0,0,0, 0,0,0,0, 0,0,0,0, 0,0,0,0};
                acc0 = __builtin_amdgcn_mfma_f32_32x32x16_bf16(xa0, yf, acc0, 0, 0, 0);
                acc1 = __builtin_amdgcn_mfma_f32_32x32x16_bf16(xa1, yf, acc1, 0, 0, 0);

                // Direct C-layout stores: reg r -> row (r&3)+8*(r>>2)+4*kh, col n / n+32.
#pragma unroll
                for (int r = 0; r < 16; ++r) {
                    long jr = jt + (r & 3) + 8 * (r >> 2) + 4 * kh;
                    float* dst = outv + jr * DDIM + n;
                    __builtin_nontemporal_store(acc0[r], dst);
                    __builtin_nontemporal_store(acc1[r], dst + 32);
                }
            }
        }
    }
    __threadfence();
    grid.sync();

    // ---------------- P3: dedup scatter of real edges ----------------
    for (int i = gid; i < NEDGE * 16; i += GRID * 256) {
        int e = i >> 4;
        int t = i & 15;
        long slot = edge_slot(ei, e);
        float4 v = *reinterpret_cast<const float4*>(ea + (long)e * DDIM + t * 4);
        float* dst = outv + slot * DDIM + t * 4;
        if (cnt[slot] == 1u) {
            float4 o = *reinterpret_cast<const float4*>(dst);
            o.x += v.x; o.y += v.y; o.z += v.z; o.w += v.w;
            *reinterpret_cast<float4*>(dst) = o;
        } else {
            unsafeAtomicAdd(dst + 0, v.x);
            unsafeAtomicAdd(dst + 1, v.y);
            unsafeAtomicAdd(dst + 2, v.z);
            unsafeAtomicAdd(dst + 3, v.w);
        }
    }
}

// ---------------------------------------------------------------------------
// Fallback path (coop launch unavailable): proven separate kernels.
// ---------------------------------------------------------------------------
__global__ __launch_bounds__(256) void fill_idx(float* __restrict__ out) {
    int gid = blockIdx.x * 256 + threadIdx.x;
    int j0 = gid << 2;
    vfloat4 rv, cv;
#pragma unroll
    for (int i = 0; i < 4; ++i) {
        int j = j0 + i;
        int g = j >> 12;
        int rem = j & 4095;
        rv[i] = (float)((g << 6) + (rem >> 6));
        cv[i] = (float)((g << 6) + (rem & 63));
    }
    __builtin_nontemporal_store(rv, reinterpret_cast<vfloat4*>(out + j0));
    __builtin_nontemporal_store(cv, reinterpret_cast<vfloat4*>(out + EF + j0));
}

__global__ __launch_bounds__(256) void pv_gemm(const float* __restrict__ pv,
                                               const float* __restrict__ W,
                                               float* __restrict__ outv) {
    int tid = threadIdx.x;
    int wv  = tid >> 6;
    int l   = tid & 63;
    int n   = l & 31;
    int kh  = l >> 5;
    long j0 = ((long)blockIdx.x * 4 + wv) * (32 * TPW);

    const float4* wp0 = reinterpret_cast<const float4*>(W + n * KDIM + kh * 8);
    const float4* wp1 = reinterpret_cast<const float4*>(W + (32 + n) * KDIM + kh * 8);
    float4 w0a = wp0[0], w0b = wp0[1], w1a = wp1[0], w1b = wp1[1];
    bf16x8 xa0, xa1;
    xa0[0]=f2bf(w0a.x); xa0[1]=f2bf(w0a.y); xa0[2]=f2bf(w0a.z); xa0[3]=f2bf(w0a.w);
    xa0[4]=f2bf(w0b.x); xa0[5]=f2bf(w0b.y); xa0[6]=f2bf(w0b.z); xa0[7]=f2bf(w0b.w);
    xa1[0]=f2bf(w1a.x); xa1[1]=f2bf(w1a.y); xa1[2]=f2bf(w1a.z); xa1[3]=f2bf(w1a.w);
    xa1[4]=f2bf(w1b.x); xa1[5]=f2bf(w1b.y); xa1[6]=f2bf(w1b.z); xa1[7]=f2bf(w1b.w);

#pragma unroll
    for (int t = 0; t < TPW; ++t) {
        long jt = j0 + t * 32;
        const float4* bp = reinterpret_cast<const float4*>(pv + (jt + n) * KDIM + kh * 8);
        float4 ba = bp[0], bb = bp[1];
        bf16x8 yf;
        yf[0]=f2bf(ba.x); yf[1]=f2bf(ba.y); yf[2]=f2bf(ba.z); yf[3]=f2bf(ba.w);
        yf[4]=f2bf(bb.x); yf[5]=f2bf(bb.y); yf[6]=f2bf(bb.z); yf[7]=f2bf(bb.w);

        f32x16 acc0 = {0,0,0,0, 0,0,0,0, 0,0,0,0, 0,0,0,0};
        f32x16 acc1 = {0,0,0,0, 0,0,0,0, 0,0,0,0, 0,0,0,0};
        acc0 = __builtin_amdgcn_mfma_f32_32x32x16_bf16(xa0, yf, acc0, 0, 0, 0);
        acc1 = __builtin_amdgcn_mfma_f32_32x32x16_bf16(xa1, yf, acc1, 0, 0, 0);
#pragma unroll
        for (int r = 0; r < 16; ++r) {
            long jr = jt + (r & 3) + 8 * (r >> 2) + 4 * kh;
            float* dst = outv + jr * DDIM + n;
            __builtin_nontemporal_store(acc0[r], dst);
            __builtin_nontemporal_store(acc1[r], dst + 32);
        }
    }
}

__global__ __launch_bounds__(256) void scatter_edges(const float* __restrict__ ea,
                                                     const int* __restrict__ ei,
                                                     float* __restrict__ outv) {
    int gid = blockIdx.x * 256 + threadIdx.x;
    int e = gid >> 4;
    int t = gid & 15;
    long slot = edge_slot(ei, e);
    float4 v = *reinterpret_cast<const float4*>(ea + (long)e * DDIM + t * 4);
    float* dst = outv + slot * DDIM + t * 4;
    unsafeAtomicAdd(dst + 0, v.x);
    unsafeAtomicAdd(dst + 1, v.y);
    unsafeAtomicAdd(dst + 2, v.z);
    unsafeAtomicAdd(dst + 3, v.w);
}

extern "C" void kernel_launch(void* const* d_in, const int* in_sizes, int n_in,
                              void* d_out, int out_size, void* d_ws, size_t ws_size,
                              hipStream_t stream) {
    const float* poly_val  = (const float*)d_in[0];   // [EF, 16]
    const float* edge_attr = (const float*)d_in[1];   // [NEDGE, 64]
    const float* W         = (const float*)d_in[2];   // [64, 16]
    // d_in[3] = poly_idx (identity slot order -> unused)
    const int*   edge_index = (const int*)d_in[4];    // [2, NEDGE]
    // d_in[5] = batch, d_in[6] = num_graphs (unused; constants fixed)

    float* out  = (float*)d_out;          // [2*EF] indices as f32, then out_val
    float* outv = out + 2 * (long)EF;     // [EF, 64]

    bool done = false;
    if (ws_size >= (size_t)EF * sizeof(unsigned)) {
        unsigned* cnt = (unsigned*)d_ws;
        void* args[7] = {(void*)&poly_val, (void*)&W, (void*)&edge_attr,
                         (void*)&edge_index, (void*)&out, (void*)&outv, (void*)&cnt};
        hipError_t err = hipLaunchCooperativeKernel((const void*)fused_all,
                                                    dim3(GRID), dim3(256),
                                                    args, 0, stream);
        done = (err == hipSuccess);
    }
    if (!done) {
        fill_idx<<<EF / 4 / 256, 256, 0, stream>>>(out);
        pv_gemm<<<PVBLK, 256, 0, stream>>>(poly_val, W, outv);
        scatter_edges<<<(NEDGE * 16) / 256, 256, 0, stream>>>(edge_attr, edge_index, outv);
    }
}

// Round 14
// 82.674 us; speedup vs baseline: 3.1076x; 3.1076x over previous
//
#include <hip/hip_runtime.h>

// Problem constants: B=128, n=64, E=65536, K=16, D=64, e_full=524288
#define EF      524288
#define NEDGE   65536
#define KDIM    16
#define DDIM    64
#define TPW     2
#define PVBLK   (EF / (32 * TPW) / 4)   // 2048 blocks, 4 waves each
#define LSTR    68

typedef float vfloat4 __attribute__((ext_vector_type(4)));
typedef short bf16x8  __attribute__((ext_vector_type(8)));
typedef float f32x16  __attribute__((ext_vector_type(16)));

__device__ __forceinline__ short f2bf(float f) {   // f32 -> bf16, RNE
    unsigned u = __float_as_uint(f);
    return (short)((u + 0x7FFFu + ((u >> 16) & 1u)) >> 16);
}

__device__ __forceinline__ long edge_slot(const int* ei, int e) {
    int r = ei[e];
    int c = ei[NEDGE + e];
    return ((long)(r >> 6) << 12) + ((long)(r & 63) << 6) + (long)(c & 63);
}

// ---------------------------------------------------------------------------
// Output 0: full_edge_index [2, EF] as float32.
// ---------------------------------------------------------------------------
__global__ __launch_bounds__(256) void fill_idx(float* __restrict__ out) {
    int gid = blockIdx.x * 256 + threadIdx.x;
    int j0 = gid << 2;
    vfloat4 rv, cv;
#pragma unroll
    for (int i = 0; i < 4; ++i) {
        int j = j0 + i;
        int g = j >> 12;
        int rem = j & 4095;
        rv[i] = (float)((g << 6) + (rem >> 6));
        cv[i] = (float)((g << 6) + (rem & 63));
    }
    __builtin_nontemporal_store(rv, reinterpret_cast<vfloat4*>(out + j0));
    __builtin_nontemporal_store(cv, reinterpret_cast<vfloat4*>(out + EF + j0));
}

// ---------------------------------------------------------------------------
// pv_gemm: R11's proven version (MFMA + LDS transpose + nt 1KB stores).
// ---------------------------------------------------------------------------
__global__ __launch_bounds__(256) void pv_gemm(const float* __restrict__ pv,
                                               const float* __restrict__ W,
                                               float* __restrict__ outv) {
    __shared__ float lds[4][32 * LSTR];
    int tid = threadIdx.x;
    int wv  = tid >> 6;
    int l   = tid & 63;
    int n   = l & 31;
    int kh  = l >> 5;
    long j0 = ((long)blockIdx.x * 4 + wv) * (32 * TPW);

    const float4* wp0 = reinterpret_cast<const float4*>(W + n * KDIM + kh * 8);
    const float4* wp1 = reinterpret_cast<const float4*>(W + (32 + n) * KDIM + kh * 8);
    float4 w0a = wp0[0], w0b = wp0[1], w1a = wp1[0], w1b = wp1[1];
    bf16x8 xa0, xa1;
    xa0[0]=f2bf(w0a.x); xa0[1]=f2bf(w0a.y); xa0[2]=f2bf(w0a.z); xa0[3]=f2bf(w0a.w);
    xa0[4]=f2bf(w0b.x); xa0[5]=f2bf(w0b.y); xa0[6]=f2bf(w0b.z); xa0[7]=f2bf(w0b.w);
    xa1[0]=f2bf(w1a.x); xa1[1]=f2bf(w1a.y); xa1[2]=f2bf(w1a.z); xa1[3]=f2bf(w1a.w);
    xa1[4]=f2bf(w1b.x); xa1[5]=f2bf(w1b.y); xa1[6]=f2bf(w1b.z); xa1[7]=f2bf(w1b.w);

    float* myl = lds[wv];
#pragma unroll
    for (int t = 0; t < TPW; ++t) {
        long jt = j0 + t * 32;
        const float4* bp = reinterpret_cast<const float4*>(pv + (jt + n) * KDIM + kh * 8);
        float4 ba = bp[0], bb = bp[1];
        bf16x8 yf;
        yf[0]=f2bf(ba.x); yf[1]=f2bf(ba.y); yf[2]=f2bf(ba.z); yf[3]=f2bf(ba.w);
        yf[4]=f2bf(bb.x); yf[5]=f2bf(bb.y); yf[6]=f2bf(bb.z); yf[7]=f2bf(bb.w);

        f32x16 acc0 = {0,0,0,0, 0,0,0,0, 0,0,0,0, 0,0,0,0};
        f32x16 acc1 = {0,0,0,0, 0,0,0,0, 0,0,0,0, 0,0,0,0};
        acc0 = __builtin_amdgcn_mfma_f32_32x32x16_bf16(xa0, yf, acc0, 0, 0, 0);
        acc1 = __builtin_amdgcn_mfma_f32_32x32x16_bf16(xa1, yf, acc1, 0, 0, 0);
#pragma unroll
        for (int q = 0; q < 4; ++q) {
            vfloat4 s0 = {acc0[4*q], acc0[4*q+1], acc0[4*q+2], acc0[4*q+3]};
            vfloat4 s1 = {acc1[4*q], acc1[4*q+1], acc1[4*q+2], acc1[4*q+3]};
            *reinterpret_cast<vfloat4*>(myl + n * LSTR + 8*q + 4*kh)      = s0;
            *reinterpret_cast<vfloat4*>(myl + n * LSTR + 32 + 8*q + 4*kh) = s1;
        }
#pragma unroll
        for (int i = 0; i < 8; ++i) {
            int row  = 4*i + (l >> 4);
            int colf = (l & 15) * 4;
            vfloat4 v = *reinterpret_cast<const vfloat4*>(myl + row * LSTR + colf);
            __builtin_nontemporal_store(v,
                reinterpret_cast<vfloat4*>(outv + (jt + row) * DDIM + colf));
        }
    }
}

// ---------------------------------------------------------------------------
// pv_probe: MEASUREMENT dispatch. Recomputes identical values (idempotent
// rewrite of outv) with PLAIN direct float4 stores (no nt, no LDS).
// Wall-time minus 57.2us baseline = this kernel's exact standalone cost.
// ---------------------------------------------------------------------------
__global__ __launch_bounds__(256) void pv_probe(const float* __restrict__ pv,
                                                const float* __restrict__ W,
                                                float* __restrict__ outv) {
    int tid = threadIdx.x;
    int wv  = tid >> 6;
    int l   = tid & 63;
    int n   = l & 31;
    int kh  = l >> 5;
    long j0 = ((long)blockIdx.x * 4 + wv) * (32 * TPW);

    const float4* wp0 = reinterpret_cast<const float4*>(W + n * KDIM + kh * 8);
    const float4* wp1 = reinterpret_cast<const float4*>(W + (32 + n) * KDIM + kh * 8);
    float4 w0a = wp0[0], w0b = wp0[1], w1a = wp1[0], w1b = wp1[1];
    bf16x8 xa0, xa1;
    xa0[0]=f2bf(w0a.x); xa0[1]=f2bf(w0a.y); xa0[2]=f2bf(w0a.z); xa0[3]=f2bf(w0a.w);
    xa0[4]=f2bf(w0b.x); xa0[5]=f2bf(w0b.y); xa0[6]=f2bf(w0b.z); xa0[7]=f2bf(w0b.w);
    xa1[0]=f2bf(w1a.x); xa1[1]=f2bf(w1a.y); xa1[2]=f2bf(w1a.z); xa1[3]=f2bf(w1a.w);
    xa1[4]=f2bf(w1b.x); xa1[5]=f2bf(w1b.y); xa1[6]=f2bf(w1b.z); xa1[7]=f2bf(w1b.w);

#pragma unroll
    for (int t = 0; t < TPW; ++t) {
        long jt = j0 + t * 32;
        const float4* bp = reinterpret_cast<const float4*>(pv + (jt + n) * KDIM + kh * 8);
        float4 ba = bp[0], bb = bp[1];
        bf16x8 yf;
        yf[0]=f2bf(ba.x); yf[1]=f2bf(ba.y); yf[2]=f2bf(ba.z); yf[3]=f2bf(ba.w);
        yf[4]=f2bf(bb.x); yf[5]=f2bf(bb.y); yf[6]=f2bf(bb.z); yf[7]=f2bf(bb.w);

        f32x16 acc0 = {0,0,0,0, 0,0,0,0, 0,0,0,0, 0,0,0,0};
        f32x16 acc1 = {0,0,0,0, 0,0,0,0, 0,0,0,0, 0,0,0,0};
        acc0 = __builtin_amdgcn_mfma_f32_32x32x16_bf16(xa0, yf, acc0, 0, 0, 0);
        acc1 = __builtin_amdgcn_mfma_f32_32x32x16_bf16(xa1, yf, acc1, 0, 0, 0);

        // Plain float4 stores in C layout: reg-quad q -> cols 8q+4kh..+3 of row jt+n.
        float* base = outv + (jt + n) * DDIM + kh * 4;
#pragma unroll
        for (int q = 0; q < 4; ++q) {
            float4 s0 = make_float4(acc0[4*q], acc0[4*q+1], acc0[4*q+2], acc0[4*q+3]);
            float4 s1 = make_float4(acc1[4*q], acc1[4*q+1], acc1[4*q+2], acc1[4*q+3]);
            *reinterpret_cast<float4*>(base + 8*q)      = s0;
            *reinterpret_cast<float4*>(base + 8*q + 32) = s1;
        }
    }
}

// ---------------------------------------------------------------------------
// Dedup scatter path (R9, proven).
// ---------------------------------------------------------------------------
__global__ __launch_bounds__(256) void zero_cnt(unsigned* __restrict__ cnt) {
    int gid = blockIdx.x * 256 + threadIdx.x;
    reinterpret_cast<uint4*>(cnt)[gid] = make_uint4(0, 0, 0, 0);
}

__global__ __launch_bounds__(256) void count_edges(const int* __restrict__ ei,
                                                   unsigned* __restrict__ cnt) {
    int e = blockIdx.x * 256 + threadIdx.x;
    atomicAdd(&cnt[edge_slot(ei, e)], 1u);
}

__global__ __launch_bounds__(256) void scatter2(const float* __restrict__ ea,
                                                const int* __restrict__ ei,
                                                const unsigned* __restrict__ cnt,
                                                float* __restrict__ outv) {
    int gid = blockIdx.x * 256 + threadIdx.x;
    int e = gid >> 4;
    int t = gid & 15;
    long slot = edge_slot(ei, e);
    float4 v = *reinterpret_cast<const float4*>(ea + (long)e * DDIM + t * 4);
    float* dst = outv + slot * DDIM + t * 4;
    if (cnt[slot] == 1u) {
        float4 o = *reinterpret_cast<const float4*>(dst);
        o.x += v.x; o.y += v.y; o.z += v.z; o.w += v.w;
        *reinterpret_cast<float4*>(dst) = o;
    } else {
        unsafeAtomicAdd(dst + 0, v.x);
        unsafeAtomicAdd(dst + 1, v.y);
        unsafeAtomicAdd(dst + 2, v.z);
        unsafeAtomicAdd(dst + 3, v.w);
    }
}

__global__ __launch_bounds__(256) void scatter_edges(const float* __restrict__ ea,
                                                     const int* __restrict__ ei,
                                                     float* __restrict__ outv) {
    int gid = blockIdx.x * 256 + threadIdx.x;
    int e = gid >> 4;
    int t = gid & 15;
    long slot = edge_slot(ei, e);
    float4 v = *reinterpret_cast<const float4*>(ea + (long)e * DDIM + t * 4);
    float* dst = outv + slot * DDIM + t * 4;
    unsafeAtomicAdd(dst + 0, v.x);
    unsafeAtomicAdd(dst + 1, v.y);
    unsafeAtomicAdd(dst + 2, v.z);
    unsafeAtomicAdd(dst + 3, v.w);
}

extern "C" void kernel_launch(void* const* d_in, const int* in_sizes, int n_in,
                              void* d_out, int out_size, void* d_ws, size_t ws_size,
                              hipStream_t stream) {
    const float* poly_val  = (const float*)d_in[0];
    const float* edge_attr = (const float*)d_in[1];
    const float* W         = (const float*)d_in[2];
    const int*   edge_index = (const int*)d_in[4];

    float* out  = (float*)d_out;
    float* outv = out + 2 * (long)EF;

    fill_idx<<<EF / 4 / 256, 256, 0, stream>>>(out);
    pv_gemm<<<PVBLK, 256, 0, stream>>>(poly_val, W, outv);
    // Probe: idempotent recompute, plain stores. Wall - 57.2us = probe cost.
    pv_probe<<<PVBLK, 256, 0, stream>>>(poly_val, W, outv);

    if (ws_size >= (size_t)EF * sizeof(unsigned)) {
        unsigned* cnt = (unsigned*)d_ws;
        zero_cnt<<<EF / 4 / 256, 256, 0, stream>>>(cnt);
        count_edges<<<NEDGE / 256, 256, 0, stream>>>(edge_index, cnt);
        scatter2<<<(NEDGE * 16) / 256, 256, 0, stream>>>(edge_attr, edge_index, cnt, outv);
    } else {
        scatter_edges<<<(NEDGE * 16) / 256, 256, 0, stream>>>(edge_attr, edge_index, outv);
    }
}

// Round 15
// 49.028 us; speedup vs baseline: 5.2402x; 1.6863x over previous
//
#include <hip/hip_runtime.h>

// Problem constants: B=128, n=64, E=65536, K=16, D=64, e_full=524288
#define EF      524288
#define NEDGE   65536
#define KDIM    16
#define DDIM    64
#define TPW     2
#define PVBLK   (EF / (32 * TPW) / 4)   // 2048 blocks, 4 waves each
#define LSTR    68
#define NTILE   (EF / 32)               // 16384 slot-tiles of 32 rows
#define CAP     64                      // edge-list capacity per tile (avg 4)

typedef float vfloat4 __attribute__((ext_vector_type(4)));
typedef short bf16x8  __attribute__((ext_vector_type(8)));
typedef float f32x16  __attribute__((ext_vector_type(16)));

__device__ __forceinline__ short f2bf(float f) {   // f32 -> bf16, RNE
    unsigned u = __float_as_uint(f);
    return (short)((u + 0x7FFFu + ((u >> 16) & 1u)) >> 16);
}

__device__ __forceinline__ long edge_slot(const int* ei, int e) {
    int r = ei[e];
    int c = ei[NEDGE + e];
    return ((long)(r >> 6) << 12) + ((long)(r & 63) << 6) + (long)(c & 63);
}

// ws layout: [0,64K) tile counts | [64K,64K+4M) lists | ovf_cnt | ovf list
#define WS_CNT_OFF   0
#define WS_LIST_OFF  (64 * 1024)
#define WS_OVFC_OFF  (WS_LIST_OFF + NTILE * CAP * 4)
#define WS_OVFL_OFF  (WS_OVFC_OFF + 4)
#define WS_NEED      (WS_OVFL_OFF + NEDGE * 4)

// ---------------------------------------------------------------------------
// Output 0: full_edge_index [2, EF] as float32.
// ---------------------------------------------------------------------------
__global__ __launch_bounds__(256) void fill_idx(float* __restrict__ out) {
    int gid = blockIdx.x * 256 + threadIdx.x;
    int j0 = gid << 2;
    vfloat4 rv, cv;
#pragma unroll
    for (int i = 0; i < 4; ++i) {
        int j = j0 + i;
        int g = j >> 12;
        int rem = j & 4095;
        rv[i] = (float)((g << 6) + (rem >> 6));
        cv[i] = (float)((g << 6) + (rem & 63));
    }
    __builtin_nontemporal_store(rv, reinterpret_cast<vfloat4*>(out + j0));
    __builtin_nontemporal_store(cv, reinterpret_cast<vfloat4*>(out + EF + j0));
}

// ---------------------------------------------------------------------------
// zero_bins: clear per-tile counts + overflow count (NTILE+1 ints).
// ---------------------------------------------------------------------------
__global__ __launch_bounds__(256) void zero_bins(unsigned* __restrict__ cnt,
                                                 unsigned* __restrict__ ovfc) {
    int gid = blockIdx.x * 256 + threadIdx.x;   // NTILE threads
    cnt[gid] = 0u;
    if (gid == 0) *ovfc = 0u;
}

// ---------------------------------------------------------------------------
// bin_edges: append (e<<5 | row_local) to the slot-tile's list.
// ---------------------------------------------------------------------------
__global__ __launch_bounds__(256) void bin_edges(const int* __restrict__ ei,
                                                 unsigned* __restrict__ cnt,
                                                 int* __restrict__ list,
                                                 unsigned* __restrict__ ovfc,
                                                 int* __restrict__ ovfl) {
    int e = blockIdx.x * 256 + threadIdx.x;     // NEDGE threads
    long slot = edge_slot(ei, e);
    int tile = (int)(slot >> 5);
    int row  = (int)(slot & 31);
    unsigned pos = atomicAdd(&cnt[tile], 1u);
    if (pos < CAP) list[tile * CAP + pos] = (e << 5) | row;
    else           ovfl[atomicAdd(ovfc, 1u)] = e;
}

// ---------------------------------------------------------------------------
// pv_fused: MFMA gemm -> LDS tile -> add binned edge rows -> dense nt stores.
// outv becomes WRITE-ONLY (no post-pass RMW); edge adds are in-LDS:
// 64 lanes x stride-1 floats (2 lanes/bank = free), avg 4 edges/tile.
// ---------------------------------------------------------------------------
__global__ __launch_bounds__(256) void pv_fused(const float* __restrict__ pv,
                                                const float* __restrict__ W,
                                                const float* __restrict__ ea,
                                                const unsigned* __restrict__ cnt,
                                                const int* __restrict__ list,
                                                float* __restrict__ outv) {
    __shared__ float lds[4][32 * LSTR];
    int tid = threadIdx.x;
    int wv  = tid >> 6;
    int l   = tid & 63;
    int n   = l & 31;
    int kh  = l >> 5;
    long j0 = ((long)blockIdx.x * 4 + wv) * (32 * TPW);

    const float4* wp0 = reinterpret_cast<const float4*>(W + n * KDIM + kh * 8);
    const float4* wp1 = reinterpret_cast<const float4*>(W + (32 + n) * KDIM + kh * 8);
    float4 w0a = wp0[0], w0b = wp0[1], w1a = wp1[0], w1b = wp1[1];
    bf16x8 xa0, xa1;
    xa0[0]=f2bf(w0a.x); xa0[1]=f2bf(w0a.y); xa0[2]=f2bf(w0a.z); xa0[3]=f2bf(w0a.w);
    xa0[4]=f2bf(w0b.x); xa0[5]=f2bf(w0b.y); xa0[6]=f2bf(w0b.z); xa0[7]=f2bf(w0b.w);
    xa1[0]=f2bf(w1a.x); xa1[1]=f2bf(w1a.y); xa1[2]=f2bf(w1a.z); xa1[3]=f2bf(w1a.w);
    xa1[4]=f2bf(w1b.x); xa1[5]=f2bf(w1b.y); xa1[6]=f2bf(w1b.z); xa1[7]=f2bf(w1b.w);

    float* myl = lds[wv];
#pragma unroll
    for (int t = 0; t < TPW; ++t) {
        long jt = j0 + t * 32;
        const float4* bp = reinterpret_cast<const float4*>(pv + (jt + n) * KDIM + kh * 8);
        float4 ba = bp[0], bb = bp[1];
        bf16x8 yf;
        yf[0]=f2bf(ba.x); yf[1]=f2bf(ba.y); yf[2]=f2bf(ba.z); yf[3]=f2bf(ba.w);
        yf[4]=f2bf(bb.x); yf[5]=f2bf(bb.y); yf[6]=f2bf(bb.z); yf[7]=f2bf(bb.w);

        f32x16 acc0 = {0,0,0,0, 0,0,0,0, 0,0,0,0, 0,0,0,0};
        f32x16 acc1 = {0,0,0,0, 0,0,0,0, 0,0,0,0, 0,0,0,0};
        acc0 = __builtin_amdgcn_mfma_f32_32x32x16_bf16(xa0, yf, acc0, 0, 0, 0);
        acc1 = __builtin_amdgcn_mfma_f32_32x32x16_bf16(xa1, yf, acc1, 0, 0, 0);

        // MFMA result -> LDS tile (col index == output col)
#pragma unroll
        for (int q = 0; q < 4; ++q) {
            vfloat4 s0 = {acc0[4*q], acc0[4*q+1], acc0[4*q+2], acc0[4*q+3]};
            vfloat4 s1 = {acc1[4*q], acc1[4*q+1], acc1[4*q+2], acc1[4*q+3]};
            *reinterpret_cast<vfloat4*>(myl + n * LSTR + 8*q + 4*kh)      = s0;
            *reinterpret_cast<vfloat4*>(myl + n * LSTR + 32 + 8*q + 4*kh) = s1;
        }
        __syncthreads();   // order LDS writes before cross-lane edge adds

        // Add this tile's binned edges into the LDS tile.
        int tile = (int)(jt >> 5);
        unsigned ec = cnt[tile];
        if (ec > CAP) ec = CAP;
        for (unsigned i = 0; i < ec; ++i) {
            int packed = list[tile * CAP + i];
            int e   = packed >> 5;
            int row = packed & 31;
            myl[row * LSTR + l] += ea[(long)e * DDIM + l];
        }
        __syncthreads();   // edge adds visible before readback

        // Dense 1KB nt stores.
#pragma unroll
        for (int i = 0; i < 8; ++i) {
            int row  = 4*i + (l >> 4);
            int colf = (l & 15) * 4;
            vfloat4 v = *reinterpret_cast<const vfloat4*>(myl + row * LSTR + colf);
            __builtin_nontemporal_store(v,
                reinterpret_cast<vfloat4*>(outv + (jt + row) * DDIM + colf));
        }
        __syncthreads();   // protect LDS tile before next t-iter overwrites
    }
}

// ---------------------------------------------------------------------------
// ovf_fix: atomic-add any overflow edges (statistically none; insurance).
// ---------------------------------------------------------------------------
__global__ __launch_bounds__(256) void ovf_fix(const float* __restrict__ ea,
                                               const int* __restrict__ ei,
                                               const unsigned* __restrict__ ovfc,
                                               const int* __restrict__ ovfl,
                                               float* __restrict__ outv) {
    unsigned nov = *ovfc;
    for (unsigned i = blockIdx.x * 256 + threadIdx.x; i < nov; i += 16 * 256) {
        int e = ovfl[i];
        long slot = edge_slot(ei, e);
        float* dst = outv + slot * DDIM;
        const float* src = ea + (long)e * DDIM;
        for (int j = 0; j < DDIM; ++j) unsafeAtomicAdd(dst + j, src[j]);
    }
}

// ---------------------------------------------------------------------------
// Fallback: R9/R11 proven path (dedup scatter) when ws too small.
// ---------------------------------------------------------------------------
__global__ __launch_bounds__(256) void pv_gemm(const float* __restrict__ pv,
                                               const float* __restrict__ W,
                                               float* __restrict__ outv) {
    __shared__ float lds[4][32 * LSTR];
    int tid = threadIdx.x;
    int wv  = tid >> 6;
    int l   = tid & 63;
    int n   = l & 31;
    int kh  = l >> 5;
    long j0 = ((long)blockIdx.x * 4 + wv) * (32 * TPW);

    const float4* wp0 = reinterpret_cast<const float4*>(W + n * KDIM + kh * 8);
    const float4* wp1 = reinterpret_cast<const float4*>(W + (32 + n) * KDIM + kh * 8);
    float4 w0a = wp0[0], w0b = wp0[1], w1a = wp1[0], w1b = wp1[1];
    bf16x8 xa0, xa1;
    xa0[0]=f2bf(w0a.x); xa0[1]=f2bf(w0a.y); xa0[2]=f2bf(w0a.z); xa0[3]=f2bf(w0a.w);
    xa0[4]=f2bf(w0b.x); xa0[5]=f2bf(w0b.y); xa0[6]=f2bf(w0b.z); xa0[7]=f2bf(w0b.w);
    xa1[0]=f2bf(w1a.x); xa1[1]=f2bf(w1a.y); xa1[2]=f2bf(w1a.z); xa1[3]=f2bf(w1a.w);
    xa1[4]=f2bf(w1b.x); xa1[5]=f2bf(w1b.y); xa1[6]=f2bf(w1b.z); xa1[7]=f2bf(w1b.w);

    float* myl = lds[wv];
#pragma unroll
    for (int t = 0; t < TPW; ++t) {
        long jt = j0 + t * 32;
        const float4* bp = reinterpret_cast<const float4*>(pv + (jt + n) * KDIM + kh * 8);
        float4 ba = bp[0], bb = bp[1];
        bf16x8 yf;
        yf[0]=f2bf(ba.x); yf[1]=f2bf(ba.y); yf[2]=f2bf(ba.z); yf[3]=f2bf(ba.w);
        yf[4]=f2bf(bb.x); yf[5]=f2bf(bb.y); yf[6]=f2bf(bb.z); yf[7]=f2bf(bb.w);

        f32x16 acc0 = {0,0,0,0, 0,0,0,0, 0,0,0,0, 0,0,0,0};
        f32x16 acc1 = {0,0,0,0, 0,0,0,0, 0,0,0,0, 0,0,0,0};
        acc0 = __builtin_amdgcn_mfma_f32_32x32x16_bf16(xa0, yf, acc0, 0, 0, 0);
        acc1 = __builtin_amdgcn_mfma_f32_32x32x16_bf16(xa1, yf, acc1, 0, 0, 0);
#pragma unroll
        for (int q = 0; q < 4; ++q) {
            vfloat4 s0 = {acc0[4*q], acc0[4*q+1], acc0[4*q+2], acc0[4*q+3]};
            vfloat4 s1 = {acc1[4*q], acc1[4*q+1], acc1[4*q+2], acc1[4*q+3]};
            *reinterpret_cast<vfloat4*>(myl + n * LSTR + 8*q + 4*kh)      = s0;
            *reinterpret_cast<vfloat4*>(myl + n * LSTR + 32 + 8*q + 4*kh) = s1;
        }
#pragma unroll
        for (int i = 0; i < 8; ++i) {
            int row  = 4*i + (l >> 4);
            int colf = (l & 15) * 4;
            vfloat4 v = *reinterpret_cast<const vfloat4*>(myl + row * LSTR + colf);
            __builtin_nontemporal_store(v,
                reinterpret_cast<vfloat4*>(outv + (jt + row) * DDIM + colf));
        }
    }
}

__global__ __launch_bounds__(256) void scatter_edges(const float* __restrict__ ea,
                                                     const int* __restrict__ ei,
                                                     float* __restrict__ outv) {
    int gid = blockIdx.x * 256 + threadIdx.x;
    int e = gid >> 4;
    int t = gid & 15;
    long slot = edge_slot(ei, e);
    float4 v = *reinterpret_cast<const float4*>(ea + (long)e * DDIM + t * 4);
    float* dst = outv + slot * DDIM + t * 4;
    unsafeAtomicAdd(dst + 0, v.x);
    unsafeAtomicAdd(dst + 1, v.y);
    unsafeAtomicAdd(dst + 2, v.z);
    unsafeAtomicAdd(dst + 3, v.w);
}

extern "C" void kernel_launch(void* const* d_in, const int* in_sizes, int n_in,
                              void* d_out, int out_size, void* d_ws, size_t ws_size,
                              hipStream_t stream) {
    const float* poly_val  = (const float*)d_in[0];
    const float* edge_attr = (const float*)d_in[1];
    const float* W         = (const float*)d_in[2];
    const int*   edge_index = (const int*)d_in[4];

    float* out  = (float*)d_out;
    float* outv = out + 2 * (long)EF;

    fill_idx<<<EF / 4 / 256, 256, 0, stream>>>(out);

    if (ws_size >= (size_t)WS_NEED) {
        char* ws = (char*)d_ws;
        unsigned* cnt  = (unsigned*)(ws + WS_CNT_OFF);
        int*      list = (int*)     (ws + WS_LIST_OFF);
        unsigned* ovfc = (unsigned*)(ws + WS_OVFC_OFF);
        int*      ovfl = (int*)     (ws + WS_OVFL_OFF);

        zero_bins<<<NTILE / 256, 256, 0, stream>>>(cnt, ovfc);
        bin_edges<<<NEDGE / 256, 256, 0, stream>>>(edge_index, cnt, list, ovfc, ovfl);
        pv_fused<<<PVBLK, 256, 0, stream>>>(poly_val, W, edge_attr, cnt, list, outv);
        ovf_fix<<<16, 256, 0, stream>>>(edge_attr, edge_index, ovfc, ovfl, outv);
    } else {
        pv_gemm<<<PVBLK, 256, 0, stream>>>(poly_val, W, outv);
        scatter_edges<<<(NEDGE * 16) / 256, 256, 0, stream>>>(edge_attr, edge_index, outv);
    }
}

// Round 16
// 47.195 us; speedup vs baseline: 5.4438x; 1.0388x over previous
//
#include <hip/hip_runtime.h>

// Problem constants: B=128, n=64, E=65536, K=16, D=64, e_full=524288
#define EF      524288
#define NEDGE   65536
#define KDIM    16
#define DDIM    64
#define TPW     2
#define PVBLK   (EF / (32 * TPW) / 4)   // 2048 blocks, 4 waves each
#define LSTR    68
#define NTILE   (EF / 32)               // 16384 slot-tiles of 32 rows
#define CAP     64                      // edge-list capacity per tile (avg 4)
#define PF      8                       // edge rows prefetched into registers

typedef float vfloat4 __attribute__((ext_vector_type(4)));
typedef short bf16x8  __attribute__((ext_vector_type(8)));
typedef float f32x16  __attribute__((ext_vector_type(16)));

__device__ __forceinline__ short f2bf(float f) {   // f32 -> bf16, RNE
    unsigned u = __float_as_uint(f);
    return (short)((u + 0x7FFFu + ((u >> 16) & 1u)) >> 16);
}

__device__ __forceinline__ long edge_slot(const int* ei, int e) {
    int r = ei[e];
    int c = ei[NEDGE + e];
    return ((long)(r >> 6) << 12) + ((long)(r & 63) << 6) + (long)(c & 63);
}

// ws layout: [0,64K) tile counts | [64K,64K+4M) lists | ovf_cnt | ovf list
#define WS_CNT_OFF   0
#define WS_LIST_OFF  (64 * 1024)
#define WS_OVFC_OFF  (WS_LIST_OFF + NTILE * CAP * 4)
#define WS_OVFL_OFF  (WS_OVFC_OFF + 4)
#define WS_NEED      (WS_OVFL_OFF + NEDGE * 4)

// ---------------------------------------------------------------------------
// fill_idx + zero_bins fused: indices are closed-form; same dispatch zeroes
// the 16384 tile counters + overflow counter (threads 0..16384).
// ---------------------------------------------------------------------------
__global__ __launch_bounds__(256) void fill_idx(float* __restrict__ out,
                                                unsigned* __restrict__ cnt,
                                                unsigned* __restrict__ ovfc) {
    int gid = blockIdx.x * 256 + threadIdx.x;   // 131072 threads
    if (gid < NTILE) cnt[gid] = 0u;
    if (gid == NTILE) *ovfc = 0u;
    int j0 = gid << 2;
    vfloat4 rv, cv;
#pragma unroll
    for (int i = 0; i < 4; ++i) {
        int j = j0 + i;
        int g = j >> 12;
        int rem = j & 4095;
        rv[i] = (float)((g << 6) + (rem >> 6));
        cv[i] = (float)((g << 6) + (rem & 63));
    }
    __builtin_nontemporal_store(rv, reinterpret_cast<vfloat4*>(out + j0));
    __builtin_nontemporal_store(cv, reinterpret_cast<vfloat4*>(out + EF + j0));
}

// ---------------------------------------------------------------------------
// bin_edges: append (e<<5 | row_local) to the slot-tile's list.
// ---------------------------------------------------------------------------
__global__ __launch_bounds__(256) void bin_edges(const int* __restrict__ ei,
                                                 unsigned* __restrict__ cnt,
                                                 int* __restrict__ list,
                                                 unsigned* __restrict__ ovfc,
                                                 int* __restrict__ ovfl) {
    int e = blockIdx.x * 256 + threadIdx.x;     // NEDGE threads
    long slot = edge_slot(ei, e);
    int tile = (int)(slot >> 5);
    int row  = (int)(slot & 31);
    unsigned pos = atomicAdd(&cnt[tile], 1u);
    if (pos < CAP) list[tile * CAP + pos] = (e << 5) | row;
    else           ovfl[atomicAdd(ovfc, 1u)] = e;
}

// ---------------------------------------------------------------------------
// pv_fused v2: NO barriers (per-wave private LDS tile; same-wave cross-lane
// LDS write->read is ordered by compiler lgkmcnt -- proven in R11) and
// register-prefetched edge rows (loads issued BEFORE the MFMA so their
// ~500cyc latency hides under compute; consumed after the LDS transpose).
// ---------------------------------------------------------------------------
__global__ __launch_bounds__(256) void pv_fused(const float* __restrict__ pv,
                                                const float* __restrict__ W,
                                                const float* __restrict__ ea,
                                                const unsigned* __restrict__ cnt,
                                                const int* __restrict__ list,
                                                float* __restrict__ outv) {
    __shared__ float lds[4][32 * LSTR];
    int tid = threadIdx.x;
    int wv  = tid >> 6;
    int l   = tid & 63;
    int n   = l & 31;
    int kh  = l >> 5;
    long j0 = ((long)blockIdx.x * 4 + wv) * (32 * TPW);

    const float4* wp0 = reinterpret_cast<const float4*>(W + n * KDIM + kh * 8);
    const float4* wp1 = reinterpret_cast<const float4*>(W + (32 + n) * KDIM + kh * 8);
    float4 w0a = wp0[0], w0b = wp0[1], w1a = wp1[0], w1b = wp1[1];
    bf16x8 xa0, xa1;
    xa0[0]=f2bf(w0a.x); xa0[1]=f2bf(w0a.y); xa0[2]=f2bf(w0a.z); xa0[3]=f2bf(w0a.w);
    xa0[4]=f2bf(w0b.x); xa0[5]=f2bf(w0b.y); xa0[6]=f2bf(w0b.z); xa0[7]=f2bf(w0b.w);
    xa1[0]=f2bf(w1a.x); xa1[1]=f2bf(w1a.y); xa1[2]=f2bf(w1a.z); xa1[3]=f2bf(w1a.w);
    xa1[4]=f2bf(w1b.x); xa1[5]=f2bf(w1b.y); xa1[6]=f2bf(w1b.z); xa1[7]=f2bf(w1b.w);

    float* myl = lds[wv];
#pragma unroll
    for (int t = 0; t < TPW; ++t) {
        long jt = j0 + t * 32;
        int tile = (int)(jt >> 5);

        // --- issue-early: edge metadata + up to PF edge rows into registers
        unsigned ec = cnt[tile];               // wave-uniform
        if (ec > CAP) ec = CAP;
        unsigned ecp = ec > PF ? PF : ec;
        float vpre[PF];
        int   rpre[PF];
#pragma unroll
        for (unsigned i = 0; i < PF; ++i) {
            if (i < ecp) {
                int packed = list[tile * CAP + i];
                rpre[i] = packed & 31;
                vpre[i] = ea[(long)(packed >> 5) * DDIM + l];
            }
        }

        // --- MFMA (edge loads in flight underneath)
        const float4* bp = reinterpret_cast<const float4*>(pv + (jt + n) * KDIM + kh * 8);
        float4 ba = bp[0], bb = bp[1];
        bf16x8 yf;
        yf[0]=f2bf(ba.x); yf[1]=f2bf(ba.y); yf[2]=f2bf(ba.z); yf[3]=f2bf(ba.w);
        yf[4]=f2bf(bb.x); yf[5]=f2bf(bb.y); yf[6]=f2bf(bb.z); yf[7]=f2bf(bb.w);

        f32x16 acc0 = {0,0,0,0, 0,0,0,0, 0,0,0,0, 0,0,0,0};
        f32x16 acc1 = {0,0,0,0, 0,0,0,0, 0,0,0,0, 0,0,0,0};
        acc0 = __builtin_amdgcn_mfma_f32_32x32x16_bf16(xa0, yf, acc0, 0, 0, 0);
        acc1 = __builtin_amdgcn_mfma_f32_32x32x16_bf16(xa1, yf, acc1, 0, 0, 0);

        // --- MFMA result -> LDS tile (per-wave private; no barrier needed)
#pragma unroll
        for (int q = 0; q < 4; ++q) {
            vfloat4 s0 = {acc0[4*q], acc0[4*q+1], acc0[4*q+2], acc0[4*q+3]};
            vfloat4 s1 = {acc1[4*q], acc1[4*q+1], acc1[4*q+2], acc1[4*q+3]};
            *reinterpret_cast<vfloat4*>(myl + n * LSTR + 8*q + 4*kh)      = s0;
            *reinterpret_cast<vfloat4*>(myl + n * LSTR + 32 + 8*q + 4*kh) = s1;
        }

        // --- consume prefetched edge rows (stride-1 across lanes: conflict-free)
#pragma unroll
        for (unsigned i = 0; i < PF; ++i) {
            if (i < ecp) myl[rpre[i] * LSTR + l] += vpre[i];
        }
        // tail (>PF edges in one tile: rare)
        for (unsigned i = PF; i < ec; ++i) {
            int packed = list[tile * CAP + i];
            myl[(packed & 31) * LSTR + l] += ea[(long)(packed >> 5) * DDIM + l];
        }

        // --- dense 1KB nt stores
#pragma unroll
        for (int i = 0; i < 8; ++i) {
            int row  = 4*i + (l >> 4);
            int colf = (l & 15) * 4;
            vfloat4 v = *reinterpret_cast<const vfloat4*>(myl + row * LSTR + colf);
            __builtin_nontemporal_store(v,
                reinterpret_cast<vfloat4*>(outv + (jt + row) * DDIM + colf));
        }
    }
}

// ---------------------------------------------------------------------------
// ovf_fix: atomic-add any overflow edges (statistically none; insurance).
// ---------------------------------------------------------------------------
__global__ __launch_bounds__(256) void ovf_fix(const float* __restrict__ ea,
                                               const int* __restrict__ ei,
                                               const unsigned* __restrict__ ovfc,
                                               const int* __restrict__ ovfl,
                                               float* __restrict__ outv) {
    unsigned nov = *ovfc;
    for (unsigned i = blockIdx.x * 256 + threadIdx.x; i < nov; i += 4 * 256) {
        int e = ovfl[i];
        long slot = edge_slot(ei, e);
        float* dst = outv + slot * DDIM;
        const float* src = ea + (long)e * DDIM;
        for (int j = 0; j < DDIM; ++j) unsafeAtomicAdd(dst + j, src[j]);
    }
}

// ---------------------------------------------------------------------------
// Fallback: R9/R11 proven path when ws too small.
// ---------------------------------------------------------------------------
__global__ __launch_bounds__(256) void pv_gemm(const float* __restrict__ pv,
                                               const float* __restrict__ W,
                                               float* __restrict__ outv) {
    __shared__ float lds[4][32 * LSTR];
    int tid = threadIdx.x;
    int wv  = tid >> 6;
    int l   = tid & 63;
    int n   = l & 31;
    int kh  = l >> 5;
    long j0 = ((long)blockIdx.x * 4 + wv) * (32 * TPW);

    const float4* wp0 = reinterpret_cast<const float4*>(W + n * KDIM + kh * 8);
    const float4* wp1 = reinterpret_cast<const float4*>(W + (32 + n) * KDIM + kh * 8);
    float4 w0a = wp0[0], w0b = wp0[1], w1a = wp1[0], w1b = wp1[1];
    bf16x8 xa0, xa1;
    xa0[0]=f2bf(w0a.x); xa0[1]=f2bf(w0a.y); xa0[2]=f2bf(w0a.z); xa0[3]=f2bf(w0a.w);
    xa0[4]=f2bf(w0b.x); xa0[5]=f2bf(w0b.y); xa0[6]=f2bf(w0b.z); xa0[7]=f2bf(w0b.w);
    xa1[0]=f2bf(w1a.x); xa1[1]=f2bf(w1a.y); xa1[2]=f2bf(w1a.z); xa1[3]=f2bf(w1a.w);
    xa1[4]=f2bf(w1b.x); xa1[5]=f2bf(w1b.y); xa1[6]=f2bf(w1b.z); xa1[7]=f2bf(w1b.w);

    float* myl = lds[wv];
#pragma unroll
    for (int t = 0; t < TPW; ++t) {
        long jt = j0 + t * 32;
        const float4* bp = reinterpret_cast<const float4*>(pv + (jt + n) * KDIM + kh * 8);
        float4 ba = bp[0], bb = bp[1];
        bf16x8 yf;
        yf[0]=f2bf(ba.x); yf[1]=f2bf(ba.y); yf[2]=f2bf(ba.z); yf[3]=f2bf(ba.w);
        yf[4]=f2bf(bb.x); yf[5]=f2bf(bb.y); yf[6]=f2bf(bb.z); yf[7]=f2bf(bb.w);

        f32x16 acc0 = {0,0,0,0, 0,0,0,0, 0,0,0,0, 0,0,0,0};
        f32x16 acc1 = {0,0,0,0, 0,0,0,0, 0,0,0,0, 0,0,0,0};
        acc0 = __builtin_amdgcn_mfma_f32_32x32x16_bf16(xa0, yf, acc0, 0, 0, 0);
        acc1 = __builtin_amdgcn_mfma_f32_32x32x16_bf16(xa1, yf, acc1, 0, 0, 0);
#pragma unroll
        for (int q = 0; q < 4; ++q) {
            vfloat4 s0 = {acc0[4*q], acc0[4*q+1], acc0[4*q+2], acc0[4*q+3]};
            vfloat4 s1 = {acc1[4*q], acc1[4*q+1], acc1[4*q+2], acc1[4*q+3]};
            *reinterpret_cast<vfloat4*>(myl + n * LSTR + 8*q + 4*kh)      = s0;
            *reinterpret_cast<vfloat4*>(myl + n * LSTR + 32 + 8*q + 4*kh) = s1;
        }
#pragma unroll
        for (int i = 0; i < 8; ++i) {
            int row  = 4*i + (l >> 4);
            int colf = (l & 15) * 4;
            vfloat4 v = *reinterpret_cast<const vfloat4*>(myl + row * LSTR + colf);
            __builtin_nontemporal_store(v,
                reinterpret_cast<vfloat4*>(outv + (jt + row) * DDIM + colf));
        }
    }
}

__global__ __launch_bounds__(256) void fill_idx_plain(float* __restrict__ out) {
    int gid = blockIdx.x * 256 + threadIdx.x;
    int j0 = gid << 2;
    vfloat4 rv, cv;
#pragma unroll
    for (int i = 0; i < 4; ++i) {
        int j = j0 + i;
        int g = j >> 12;
        int rem = j & 4095;
        rv[i] = (float)((g << 6) + (rem >> 6));
        cv[i] = (float)((g << 6) + (rem & 63));
    }
    __builtin_nontemporal_store(rv, reinterpret_cast<vfloat4*>(out + j0));
    __builtin_nontemporal_store(cv, reinterpret_cast<vfloat4*>(out + EF + j0));
}

__global__ __launch_bounds__(256) void scatter_edges(const float* __restrict__ ea,
                                                     const int* __restrict__ ei,
                                                     float* __restrict__ outv) {
    int gid = blockIdx.x * 256 + threadIdx.x;
    int e = gid >> 4;
    int t = gid & 15;
    long slot = edge_slot(ei, e);
    float4 v = *reinterpret_cast<const float4*>(ea + (long)e * DDIM + t * 4);
    float* dst = outv + slot * DDIM + t * 4;
    unsafeAtomicAdd(dst + 0, v.x);
    unsafeAtomicAdd(dst + 1, v.y);
    unsafeAtomicAdd(dst + 2, v.z);
    unsafeAtomicAdd(dst + 3, v.w);
}

extern "C" void kernel_launch(void* const* d_in, const int* in_sizes, int n_in,
                              void* d_out, int out_size, void* d_ws, size_t ws_size,
                              hipStream_t stream) {
    const float* poly_val  = (const float*)d_in[0];
    const float* edge_attr = (const float*)d_in[1];
    const float* W         = (const float*)d_in[2];
    const int*   edge_index = (const int*)d_in[4];

    float* out  = (float*)d_out;
    float* outv = out + 2 * (long)EF;

    if (ws_size >= (size_t)WS_NEED) {
        char* ws = (char*)d_ws;
        unsigned* cnt  = (unsigned*)(ws + WS_CNT_OFF);
        int*      list = (int*)     (ws + WS_LIST_OFF);
        unsigned* ovfc = (unsigned*)(ws + WS_OVFC_OFF);
        int*      ovfl = (int*)     (ws + WS_OVFL_OFF);

        fill_idx<<<EF / 4 / 256, 256, 0, stream>>>(out, cnt, ovfc);
        bin_edges<<<NEDGE / 256, 256, 0, stream>>>(edge_index, cnt, list, ovfc, ovfl);
        pv_fused<<<PVBLK, 256, 0, stream>>>(poly_val, W, edge_attr, cnt, list, outv);
        ovf_fix<<<4, 256, 0, stream>>>(edge_attr, edge_index, ovfc, ovfl, outv);
    } else {
        fill_idx_plain<<<EF / 4 / 256, 256, 0, stream>>>(out);
        pv_gemm<<<PVBLK, 256, 0, stream>>>(poly_val, W, outv);
        scatter_edges<<<(NEDGE * 16) / 256, 256, 0, stream>>>(edge_attr, edge_index, outv);
    }
}

// Round 17
// 46.652 us; speedup vs baseline: 5.5072x; 1.0116x over previous
//
#include <hip/hip_runtime.h>

// Problem constants: B=128, n=64, E=65536, K=16, D=64, e_full=524288
#define EF      524288
#define NEDGE   65536
#define KDIM    16
#define DDIM    64
#define TPW     2
#define PVBLK   (EF / (32 * TPW) / 4)   // 2048 blocks, 4 waves each
#define LSTR    68
#define NTILE   (EF / 32)               // 16384 slot-tiles of 32 rows
#define CAP     64                      // edge-list capacity per tile (avg 4)
#define PF      8                       // edge rows prefetched into registers

typedef float vfloat4 __attribute__((ext_vector_type(4)));
typedef short bf16x8  __attribute__((ext_vector_type(8)));
typedef float f32x16  __attribute__((ext_vector_type(16)));

__device__ __forceinline__ short f2bf(float f) {   // f32 -> bf16, RNE
    unsigned u = __float_as_uint(f);
    return (short)((u + 0x7FFFu + ((u >> 16) & 1u)) >> 16);
}

__device__ __forceinline__ long edge_slot(const int* ei, int e) {
    int r = ei[e];
    int c = ei[NEDGE + e];
    return ((long)(r >> 6) << 12) + ((long)(r & 63) << 6) + (long)(c & 63);
}

// ws layout: [0,64K) tile counts | [64K,64K+4M) lists | ovf_cnt | ovf list
#define WS_CNT_OFF   0
#define WS_LIST_OFF  (64 * 1024)
#define WS_OVFC_OFF  (WS_LIST_OFF + NTILE * CAP * 4)
#define WS_OVFL_OFF  (WS_OVFC_OFF + 4)
#define WS_NEED      (WS_OVFL_OFF + NEDGE * 4)

// ---------------------------------------------------------------------------
// fill_idx + zero_bins fused. PLAIN stores: the 4 MB index block is rewritten
// identically every replay -> let L2/L3 absorb it (NT forced it to HBM).
// ---------------------------------------------------------------------------
__global__ __launch_bounds__(256) void fill_idx(float* __restrict__ out,
                                                unsigned* __restrict__ cnt,
                                                unsigned* __restrict__ ovfc) {
    int gid = blockIdx.x * 256 + threadIdx.x;   // 131072 threads
    if (gid < NTILE) cnt[gid] = 0u;
    if (gid == NTILE) *ovfc = 0u;
    int j0 = gid << 2;
    vfloat4 rv, cv;
#pragma unroll
    for (int i = 0; i < 4; ++i) {
        int j = j0 + i;
        int g = j >> 12;
        int rem = j & 4095;
        rv[i] = (float)((g << 6) + (rem >> 6));
        cv[i] = (float)((g << 6) + (rem & 63));
    }
    *reinterpret_cast<vfloat4*>(out + j0)      = rv;
    *reinterpret_cast<vfloat4*>(out + EF + j0) = cv;
}

// ---------------------------------------------------------------------------
// bin_edges: append (e<<5 | row_local) to the slot-tile's list.
// ---------------------------------------------------------------------------
__global__ __launch_bounds__(256) void bin_edges(const int* __restrict__ ei,
                                                 unsigned* __restrict__ cnt,
                                                 int* __restrict__ list,
                                                 unsigned* __restrict__ ovfc,
                                                 int* __restrict__ ovfl) {
    int e = blockIdx.x * 256 + threadIdx.x;     // NEDGE threads
    long slot = edge_slot(ei, e);
    int tile = (int)(slot >> 5);
    int row  = (int)(slot & 31);
    unsigned pos = atomicAdd(&cnt[tile], 1u);
    if (pos < CAP) list[tile * CAP + pos] = (e << 5) | row;
    else           ovfl[atomicAdd(ovfc, 1u)] = e;
}

// ---------------------------------------------------------------------------
// pv_fused v3 = v2 with PLAIN stores (NT removed). outv (128 MB) is rewritten
// every replay; with plain stores the write stream re-dirties L2/L3-resident
// lines instead of being forced to HBM each replay (R13 counters: WRITE_SIZE
// 161 MB/replay under NT while reads were fully L3-absorbed).
// ---------------------------------------------------------------------------
__global__ __launch_bounds__(256) void pv_fused(const float* __restrict__ pv,
                                                const float* __restrict__ W,
                                                const float* __restrict__ ea,
                                                const unsigned* __restrict__ cnt,
                                                const int* __restrict__ list,
                                                float* __restrict__ outv) {
    __shared__ float lds[4][32 * LSTR];
    int tid = threadIdx.x;
    int wv  = tid >> 6;
    int l   = tid & 63;
    int n   = l & 31;
    int kh  = l >> 5;
    long j0 = ((long)blockIdx.x * 4 + wv) * (32 * TPW);

    const float4* wp0 = reinterpret_cast<const float4*>(W + n * KDIM + kh * 8);
    const float4* wp1 = reinterpret_cast<const float4*>(W + (32 + n) * KDIM + kh * 8);
    float4 w0a = wp0[0], w0b = wp0[1], w1a = wp1[0], w1b = wp1[1];
    bf16x8 xa0, xa1;
    xa0[0]=f2bf(w0a.x); xa0[1]=f2bf(w0a.y); xa0[2]=f2bf(w0a.z); xa0[3]=f2bf(w0a.w);
    xa0[4]=f2bf(w0b.x); xa0[5]=f2bf(w0b.y); xa0[6]=f2bf(w0b.z); xa0[7]=f2bf(w0b.w);
    xa1[0]=f2bf(w1a.x); xa1[1]=f2bf(w1a.y); xa1[2]=f2bf(w1a.z); xa1[3]=f2bf(w1a.w);
    xa1[4]=f2bf(w1b.x); xa1[5]=f2bf(w1b.y); xa1[6]=f2bf(w1b.z); xa1[7]=f2bf(w1b.w);

    float* myl = lds[wv];
#pragma unroll
    for (int t = 0; t < TPW; ++t) {
        long jt = j0 + t * 32;
        int tile = (int)(jt >> 5);

        // --- issue-early: edge metadata + up to PF edge rows into registers
        unsigned ec = cnt[tile];               // wave-uniform
        if (ec > CAP) ec = CAP;
        unsigned ecp = ec > PF ? PF : ec;
        float vpre[PF];
        int   rpre[PF];
#pragma unroll
        for (unsigned i = 0; i < PF; ++i) {
            if (i < ecp) {
                int packed = list[tile * CAP + i];
                rpre[i] = packed & 31;
                vpre[i] = ea[(long)(packed >> 5) * DDIM + l];
            }
        }

        // --- MFMA (edge loads in flight underneath)
        const float4* bp = reinterpret_cast<const float4*>(pv + (jt + n) * KDIM + kh * 8);
        float4 ba = bp[0], bb = bp[1];
        bf16x8 yf;
        yf[0]=f2bf(ba.x); yf[1]=f2bf(ba.y); yf[2]=f2bf(ba.z); yf[3]=f2bf(ba.w);
        yf[4]=f2bf(bb.x); yf[5]=f2bf(bb.y); yf[6]=f2bf(bb.z); yf[7]=f2bf(bb.w);

        f32x16 acc0 = {0,0,0,0, 0,0,0,0, 0,0,0,0, 0,0,0,0};
        f32x16 acc1 = {0,0,0,0, 0,0,0,0, 0,0,0,0, 0,0,0,0};
        acc0 = __builtin_amdgcn_mfma_f32_32x32x16_bf16(xa0, yf, acc0, 0, 0, 0);
        acc1 = __builtin_amdgcn_mfma_f32_32x32x16_bf16(xa1, yf, acc1, 0, 0, 0);

        // --- MFMA result -> LDS tile (per-wave private; no barrier needed)
#pragma unroll
        for (int q = 0; q < 4; ++q) {
            vfloat4 s0 = {acc0[4*q], acc0[4*q+1], acc0[4*q+2], acc0[4*q+3]};
            vfloat4 s1 = {acc1[4*q], acc1[4*q+1], acc1[4*q+2], acc1[4*q+3]};
            *reinterpret_cast<vfloat4*>(myl + n * LSTR + 8*q + 4*kh)      = s0;
            *reinterpret_cast<vfloat4*>(myl + n * LSTR + 32 + 8*q + 4*kh) = s1;
        }

        // --- consume prefetched edge rows (stride-1 across lanes: conflict-free)
#pragma unroll
        for (unsigned i = 0; i < PF; ++i) {
            if (i < ecp) myl[rpre[i] * LSTR + l] += vpre[i];
        }
        // tail (>PF edges in one tile: rare)
        for (unsigned i = PF; i < ec; ++i) {
            int packed = list[tile * CAP + i];
            myl[(packed & 31) * LSTR + l] += ea[(long)(packed >> 5) * DDIM + l];
        }

        // --- dense 1KB stores (plain: let L2/L3 absorb the replayed stream)
#pragma unroll
        for (int i = 0; i < 8; ++i) {
            int row  = 4*i + (l >> 4);
            int colf = (l & 15) * 4;
            vfloat4 v = *reinterpret_cast<const vfloat4*>(myl + row * LSTR + colf);
            *reinterpret_cast<vfloat4*>(outv + (jt + row) * DDIM + colf) = v;
        }
    }
}

// ---------------------------------------------------------------------------
// ovf_fix: atomic-add any overflow edges (statistically none; insurance).
// ---------------------------------------------------------------------------
__global__ __launch_bounds__(256) void ovf_fix(const float* __restrict__ ea,
                                               const int* __restrict__ ei,
                                               const unsigned* __restrict__ ovfc,
                                               const int* __restrict__ ovfl,
                                               float* __restrict__ outv) {
    unsigned nov = *ovfc;
    for (unsigned i = blockIdx.x * 256 + threadIdx.x; i < nov; i += 4 * 256) {
        int e = ovfl[i];
        long slot = edge_slot(ei, e);
        float* dst = outv + slot * DDIM;
        const float* src = ea + (long)e * DDIM;
        for (int j = 0; j < DDIM; ++j) unsafeAtomicAdd(dst + j, src[j]);
    }
}

// ---------------------------------------------------------------------------
// Fallback: R9/R11 proven path when ws too small.
// ---------------------------------------------------------------------------
__global__ __launch_bounds__(256) void pv_gemm(const float* __restrict__ pv,
                                               const float* __restrict__ W,
                                               float* __restrict__ outv) {
    __shared__ float lds[4][32 * LSTR];
    int tid = threadIdx.x;
    int wv  = tid >> 6;
    int l   = tid & 63;
    int n   = l & 31;
    int kh  = l >> 5;
    long j0 = ((long)blockIdx.x * 4 + wv) * (32 * TPW);

    const float4* wp0 = reinterpret_cast<const float4*>(W + n * KDIM + kh * 8);
    const float4* wp1 = reinterpret_cast<const float4*>(W + (32 + n) * KDIM + kh * 8);
    float4 w0a = wp0[0], w0b = wp0[1], w1a = wp1[0], w1b = wp1[1];
    bf16x8 xa0, xa1;
    xa0[0]=f2bf(w0a.x); xa0[1]=f2bf(w0a.y); xa0[2]=f2bf(w0a.z); xa0[3]=f2bf(w0a.w);
    xa0[4]=f2bf(w0b.x); xa0[5]=f2bf(w0b.y); xa0[6]=f2bf(w0b.z); xa0[7]=f2bf(w0b.w);
    xa1[0]=f2bf(w1a.x); xa1[1]=f2bf(w1a.y); xa1[2]=f2bf(w1a.z); xa1[3]=f2bf(w1a.w);
    xa1[4]=f2bf(w1b.x); xa1[5]=f2bf(w1b.y); xa1[6]=f2bf(w1b.z); xa1[7]=f2bf(w1b.w);

    float* myl = lds[wv];
#pragma unroll
    for (int t = 0; t < TPW; ++t) {
        long jt = j0 + t * 32;
        const float4* bp = reinterpret_cast<const float4*>(pv + (jt + n) * KDIM + kh * 8);
        float4 ba = bp[0], bb = bp[1];
        bf16x8 yf;
        yf[0]=f2bf(ba.x); yf[1]=f2bf(ba.y); yf[2]=f2bf(ba.z); yf[3]=f2bf(ba.w);
        yf[4]=f2bf(bb.x); yf[5]=f2bf(bb.y); yf[6]=f2bf(bb.z); yf[7]=f2bf(bb.w);

        f32x16 acc0 = {0,0,0,0, 0,0,0,0, 0,0,0,0, 0,0,0,0};
        f32x16 acc1 = {0,0,0,0, 0,0,0,0, 0,0,0,0, 0,0,0,0};
        acc0 = __builtin_amdgcn_mfma_f32_32x32x16_bf16(xa0, yf, acc0, 0, 0, 0);
        acc1 = __builtin_amdgcn_mfma_f32_32x32x16_bf16(xa1, yf, acc1, 0, 0, 0);
#pragma unroll
        for (int q = 0; q < 4; ++q) {
            vfloat4 s0 = {acc0[4*q], acc0[4*q+1], acc0[4*q+2], acc0[4*q+3]};
            vfloat4 s1 = {acc1[4*q], acc1[4*q+1], acc1[4*q+2], acc1[4*q+3]};
            *reinterpret_cast<vfloat4*>(myl + n * LSTR + 8*q + 4*kh)      = s0;
            *reinterpret_cast<vfloat4*>(myl + n * LSTR + 32 + 8*q + 4*kh) = s1;
        }
#pragma unroll
        for (int i = 0; i < 8; ++i) {
            int row  = 4*i + (l >> 4);
            int colf = (l & 15) * 4;
            vfloat4 v = *reinterpret_cast<const vfloat4*>(myl + row * LSTR + colf);
            *reinterpret_cast<vfloat4*>(outv + (jt + row) * DDIM + colf) = v;
        }
    }
}

__global__ __launch_bounds__(256) void fill_idx_plain(float* __restrict__ out) {
    int gid = blockIdx.x * 256 + threadIdx.x;
    int j0 = gid << 2;
    vfloat4 rv, cv;
#pragma unroll
    for (int i = 0; i < 4; ++i) {
        int j = j0 + i;
        int g = j >> 12;
        int rem = j & 4095;
        rv[i] = (float)((g << 6) + (rem >> 6));
        cv[i] = (float)((g << 6) + (rem & 63));
    }
    *reinterpret_cast<vfloat4*>(out + j0)      = rv;
    *reinterpret_cast<vfloat4*>(out + EF + j0) = cv;
}

__global__ __launch_bounds__(256) void scatter_edges(const float* __restrict__ ea,
                                                     const int* __restrict__ ei,
                                                     float* __restrict__ outv) {
    int gid = blockIdx.x * 256 + threadIdx.x;
    int e = gid >> 4;
    int t = gid & 15;
    long slot = edge_slot(ei, e);
    float4 v = *reinterpret_cast<const float4*>(ea + (long)e * DDIM + t * 4);
    float* dst = outv + slot * DDIM + t * 4;
    unsafeAtomicAdd(dst + 0, v.x);
    unsafeAtomicAdd(dst + 1, v.y);
    unsafeAtomicAdd(dst + 2, v.z);
    unsafeAtomicAdd(dst + 3, v.w);
}

extern "C" void kernel_launch(void* const* d_in, const int* in_sizes, int n_in,
                              void* d_out, int out_size, void* d_ws, size_t ws_size,
                              hipStream_t stream) {
    const float* poly_val  = (const float*)d_in[0];
    const float* edge_attr = (const float*)d_in[1];
    const float* W         = (const float*)d_in[2];
    const int*   edge_index = (const int*)d_in[4];

    float* out  = (float*)d_out;
    float* outv = out + 2 * (long)EF;

    if (ws_size >= (size_t)WS_NEED) {
        char* ws = (char*)d_ws;
        unsigned* cnt  = (unsigned*)(ws + WS_CNT_OFF);
        int*      list = (int*)     (ws + WS_LIST_OFF);
        unsigned* ovfc = (unsigned*)(ws + WS_OVFC_OFF);
        int*      ovfl = (int*)     (ws + WS_OVFL_OFF);

        fill_idx<<<EF / 4 / 256, 256, 0, stream>>>(out, cnt, ovfc);
        bin_edges<<<NEDGE / 256, 256, 0, stream>>>(edge_index, cnt, list, ovfc, ovfl);
        pv_fused<<<PVBLK, 256, 0, stream>>>(poly_val, W, edge_attr, cnt, list, outv);
        ovf_fix<<<4, 256, 0, stream>>>(edge_attr, edge_index, ovfc, ovfl, outv);
    } else {
        fill_idx_plain<<<EF / 4 / 256, 256, 0, stream>>>(out);
        pv_gemm<<<PVBLK, 256, 0, stream>>>(poly_val, W, outv);
        scatter_edges<<<(NEDGE * 16) / 256, 256, 0, stream>>>(edge_attr, edge_index, outv);
    }
}

// Round 18
// 45.416 us; speedup vs baseline: 5.6570x; 1.0272x over previous
//
#include <hip/hip_runtime.h>

// Problem constants: B=128, n=64, E=65536, K=16, D=64, e_full=524288
#define EF      524288
#define NEDGE   65536
#define KDIM    16
#define DDIM    64
#define TPW     2
#define PVBLK   (EF / (32 * TPW) / 4)   // 2048 blocks, 4 waves each
#define LSTR    68
#define NTILE   (EF / 32)               // 16384 slot-tiles of 32 rows
#define CAP     64                      // edge-list capacity per tile (avg 4)
#define PF      8                       // edge rows prefetched into registers

typedef float vfloat4 __attribute__((ext_vector_type(4)));
typedef short bf16x8  __attribute__((ext_vector_type(8)));
typedef float f32x16  __attribute__((ext_vector_type(16)));

__device__ __forceinline__ short f2bf(float f) {   // f32 -> bf16, RNE
    unsigned u = __float_as_uint(f);
    return (short)((u + 0x7FFFu + ((u >> 16) & 1u)) >> 16);
}

__device__ __forceinline__ long edge_slot(const int* ei, int e) {
    int r = ei[e];
    int c = ei[NEDGE + e];
    return ((long)(r >> 6) << 12) + ((long)(r & 63) << 6) + (long)(c & 63);
}

// ws layout: [0,64K) tile counts | [64K,64K+4M) lists | ovf_cnt | ovf list
#define WS_CNT_OFF   0
#define WS_LIST_OFF  (64 * 1024)
#define WS_OVFC_OFF  (WS_LIST_OFF + NTILE * CAP * 4)
#define WS_OVFL_OFF  (WS_OVFC_OFF + 4)
#define WS_NEED      (WS_OVFL_OFF + NEDGE * 4)

// ---------------------------------------------------------------------------
// fill_idx + zero_bins fused (plain stores).
// ---------------------------------------------------------------------------
__global__ __launch_bounds__(256) void fill_idx(float* __restrict__ out,
                                                unsigned* __restrict__ cnt,
                                                unsigned* __restrict__ ovfc) {
    int gid = blockIdx.x * 256 + threadIdx.x;   // 131072 threads
    if (gid < NTILE) cnt[gid] = 0u;
    if (gid == NTILE) *ovfc = 0u;
    int j0 = gid << 2;
    vfloat4 rv, cv;
#pragma unroll
    for (int i = 0; i < 4; ++i) {
        int j = j0 + i;
        int g = j >> 12;
        int rem = j & 4095;
        rv[i] = (float)((g << 6) + (rem >> 6));
        cv[i] = (float)((g << 6) + (rem & 63));
    }
    *reinterpret_cast<vfloat4*>(out + j0)      = rv;
    *reinterpret_cast<vfloat4*>(out + EF + j0) = cv;
}

// ---------------------------------------------------------------------------
// bin_edges: append (e<<5 | row_local) to the slot-tile's list.
// ---------------------------------------------------------------------------
__global__ __launch_bounds__(256) void bin_edges(const int* __restrict__ ei,
                                                 unsigned* __restrict__ cnt,
                                                 int* __restrict__ list,
                                                 unsigned* __restrict__ ovfc,
                                                 int* __restrict__ ovfl) {
    int e = blockIdx.x * 256 + threadIdx.x;     // NEDGE threads
    long slot = edge_slot(ei, e);
    int tile = (int)(slot >> 5);
    int row  = (int)(slot & 31);
    unsigned pos = atomicAdd(&cnt[tile], 1u);
    if (pos < CAP) list[tile * CAP + pos] = (e << 5) | row;
    else           ovfl[atomicAdd(ovfc, 1u)] = e;
}

// ---------------------------------------------------------------------------
// pv_fused v4: FULL software pipeline of the edge chain. All independent
// loads for BOTH tiles (cnt x2, list entries x2*PF unconditionally -- always
// in-bounds, values past ec unused -- then predicated ea rows x2*PF, and both
// pv fragments) are issued at the TOP of the wave's work. t=0's chain hides
// under W setup + MFMA; t=1's chain hides under all of t=0's compute+stores.
// ---------------------------------------------------------------------------
__global__ __launch_bounds__(256) void pv_fused(const float* __restrict__ pv,
                                                const float* __restrict__ W,
                                                const float* __restrict__ ea,
                                                const unsigned* __restrict__ cnt,
                                                const int* __restrict__ list,
                                                float* __restrict__ outv) {
    __shared__ float lds[4][32 * LSTR];
    int tid = threadIdx.x;
    int wv  = tid >> 6;
    int l   = tid & 63;
    int n   = l & 31;
    int kh  = l >> 5;
    long j0 = ((long)blockIdx.x * 4 + wv) * (32 * TPW);
    int tile0 = (int)(j0 >> 5);

    // ---- issue-early phase: every independent load, maximum MLP ----
    unsigned ec0 = cnt[tile0];          // 2 independent loads
    unsigned ec1 = cnt[tile0 + 1];

    int pk0[PF], pk1[PF];               // unconditional: in-bounds within CAP
#pragma unroll
    for (int i = 0; i < PF; ++i) {
        pk0[i] = list[(long)tile0 * CAP + i];
        pk1[i] = list[(long)(tile0 + 1) * CAP + i];
    }

    if (ec0 > CAP) ec0 = CAP;
    if (ec1 > CAP) ec1 = CAP;
    unsigned ep0 = ec0 > PF ? PF : ec0;
    unsigned ep1 = ec1 > PF ? PF : ec1;

    float vpre0[PF], vpre1[PF];         // predicated ea rows (256B coalesced)
#pragma unroll
    for (int i = 0; i < PF; ++i) {
        if ((unsigned)i < ep0) vpre0[i] = ea[(long)(pk0[i] >> 5) * DDIM + l];
        if ((unsigned)i < ep1) vpre1[i] = ea[(long)(pk1[i] >> 5) * DDIM + l];
    }

    // both tiles' pv fragments
    const float4* bp0 = reinterpret_cast<const float4*>(pv + (j0 + n) * KDIM + kh * 8);
    const float4* bp1 = reinterpret_cast<const float4*>(pv + (j0 + 32 + n) * KDIM + kh * 8);
    float4 ba0 = bp0[0], bb0 = bp0[1], ba1 = bp1[0], bb1 = bp1[1];

    // W fragments (L1-resident)
    const float4* wp0 = reinterpret_cast<const float4*>(W + n * KDIM + kh * 8);
    const float4* wp1 = reinterpret_cast<const float4*>(W + (32 + n) * KDIM + kh * 8);
    float4 w0a = wp0[0], w0b = wp0[1], w1a = wp1[0], w1b = wp1[1];
    bf16x8 xa0, xa1;
    xa0[0]=f2bf(w0a.x); xa0[1]=f2bf(w0a.y); xa0[2]=f2bf(w0a.z); xa0[3]=f2bf(w0a.w);
    xa0[4]=f2bf(w0b.x); xa0[5]=f2bf(w0b.y); xa0[6]=f2bf(w0b.z); xa0[7]=f2bf(w0b.w);
    xa1[0]=f2bf(w1a.x); xa1[1]=f2bf(w1a.y); xa1[2]=f2bf(w1a.z); xa1[3]=f2bf(w1a.w);
    xa1[4]=f2bf(w1b.x); xa1[5]=f2bf(w1b.y); xa1[6]=f2bf(w1b.z); xa1[7]=f2bf(w1b.w);

    float* myl = lds[wv];

    // ================= tile 0 =================
    {
        bf16x8 yf;
        yf[0]=f2bf(ba0.x); yf[1]=f2bf(ba0.y); yf[2]=f2bf(ba0.z); yf[3]=f2bf(ba0.w);
        yf[4]=f2bf(bb0.x); yf[5]=f2bf(bb0.y); yf[6]=f2bf(bb0.z); yf[7]=f2bf(bb0.w);
        f32x16 acc0 = {0,0,0,0, 0,0,0,0, 0,0,0,0, 0,0,0,0};
        f32x16 acc1 = {0,0,0,0, 0,0,0,0, 0,0,0,0, 0,0,0,0};
        acc0 = __builtin_amdgcn_mfma_f32_32x32x16_bf16(xa0, yf, acc0, 0, 0, 0);
        acc1 = __builtin_amdgcn_mfma_f32_32x32x16_bf16(xa1, yf, acc1, 0, 0, 0);
#pragma unroll
        for (int q = 0; q < 4; ++q) {
            vfloat4 s0 = {acc0[4*q], acc0[4*q+1], acc0[4*q+2], acc0[4*q+3]};
            vfloat4 s1 = {acc1[4*q], acc1[4*q+1], acc1[4*q+2], acc1[4*q+3]};
            *reinterpret_cast<vfloat4*>(myl + n * LSTR + 8*q + 4*kh)      = s0;
            *reinterpret_cast<vfloat4*>(myl + n * LSTR + 32 + 8*q + 4*kh) = s1;
        }
#pragma unroll
        for (int i = 0; i < PF; ++i)
            if ((unsigned)i < ep0) myl[(pk0[i] & 31) * LSTR + l] += vpre0[i];
        for (unsigned i = PF; i < ec0; ++i) {     // rare tail
            int packed = list[(long)tile0 * CAP + i];
            myl[(packed & 31) * LSTR + l] += ea[(long)(packed >> 5) * DDIM + l];
        }
#pragma unroll
        for (int i = 0; i < 8; ++i) {
            int row  = 4*i + (l >> 4);
            int colf = (l & 15) * 4;
            vfloat4 v = *reinterpret_cast<const vfloat4*>(myl + row * LSTR + colf);
            *reinterpret_cast<vfloat4*>(outv + (j0 + row) * DDIM + colf) = v;
        }
    }

    // ================= tile 1 =================
    {
        bf16x8 yf;
        yf[0]=f2bf(ba1.x); yf[1]=f2bf(ba1.y); yf[2]=f2bf(ba1.z); yf[3]=f2bf(ba1.w);
        yf[4]=f2bf(bb1.x); yf[5]=f2bf(bb1.y); yf[6]=f2bf(bb1.z); yf[7]=f2bf(bb1.w);
        f32x16 acc0 = {0,0,0,0, 0,0,0,0, 0,0,0,0, 0,0,0,0};
        f32x16 acc1 = {0,0,0,0, 0,0,0,0, 0,0,0,0, 0,0,0,0};
        acc0 = __builtin_amdgcn_mfma_f32_32x32x16_bf16(xa0, yf, acc0, 0, 0, 0);
        acc1 = __builtin_amdgcn_mfma_f32_32x32x16_bf16(xa1, yf, acc1, 0, 0, 0);
#pragma unroll
        for (int q = 0; q < 4; ++q) {
            vfloat4 s0 = {acc0[4*q], acc0[4*q+1], acc0[4*q+2], acc0[4*q+3]};
            vfloat4 s1 = {acc1[4*q], acc1[4*q+1], acc1[4*q+2], acc1[4*q+3]};
            *reinterpret_cast<vfloat4*>(myl + n * LSTR + 8*q + 4*kh)      = s0;
            *reinterpret_cast<vfloat4*>(myl + n * LSTR + 32 + 8*q + 4*kh) = s1;
        }
#pragma unroll
        for (int i = 0; i < PF; ++i)
            if ((unsigned)i < ep1) myl[(pk1[i] & 31) * LSTR + l] += vpre1[i];
        for (unsigned i = PF; i < ec1; ++i) {     // rare tail
            int packed = list[(long)(tile0 + 1) * CAP + i];
            myl[(packed & 31) * LSTR + l] += ea[(long)(packed >> 5) * DDIM + l];
        }
#pragma unroll
        for (int i = 0; i < 8; ++i) {
            int row  = 4*i + (l >> 4);
            int colf = (l & 15) * 4;
            vfloat4 v = *reinterpret_cast<const vfloat4*>(myl + row * LSTR + colf);
            *reinterpret_cast<vfloat4*>(outv + (j0 + 32 + row) * DDIM + colf) = v;
        }
    }
}

// ---------------------------------------------------------------------------
// ovf_fix: atomic-add any overflow edges (statistically none; insurance).
// ---------------------------------------------------------------------------
__global__ __launch_bounds__(256) void ovf_fix(const float* __restrict__ ea,
                                               const int* __restrict__ ei,
                                               const unsigned* __restrict__ ovfc,
                                               const int* __restrict__ ovfl,
                                               float* __restrict__ outv) {
    unsigned nov = *ovfc;
    for (unsigned i = blockIdx.x * 256 + threadIdx.x; i < nov; i += 4 * 256) {
        int e = ovfl[i];
        long slot = edge_slot(ei, e);
        float* dst = outv + slot * DDIM;
        const float* src = ea + (long)e * DDIM;
        for (int j = 0; j < DDIM; ++j) unsafeAtomicAdd(dst + j, src[j]);
    }
}

// ---------------------------------------------------------------------------
// Fallback: proven separate path when ws too small.
// ---------------------------------------------------------------------------
__global__ __launch_bounds__(256) void pv_gemm(const float* __restrict__ pv,
                                               const float* __restrict__ W,
                                               float* __restrict__ outv) {
    __shared__ float lds[4][32 * LSTR];
    int tid = threadIdx.x;
    int wv  = tid >> 6;
    int l   = tid & 63;
    int n   = l & 31;
    int kh  = l >> 5;
    long j0 = ((long)blockIdx.x * 4 + wv) * (32 * TPW);

    const float4* wp0 = reinterpret_cast<const float4*>(W + n * KDIM + kh * 8);
    const float4* wp1 = reinterpret_cast<const float4*>(W + (32 + n) * KDIM + kh * 8);
    float4 w0a = wp0[0], w0b = wp0[1], w1a = wp1[0], w1b = wp1[1];
    bf16x8 xa0, xa1;
    xa0[0]=f2bf(w0a.x); xa0[1]=f2bf(w0a.y); xa0[2]=f2bf(w0a.z); xa0[3]=f2bf(w0a.w);
    xa0[4]=f2bf(w0b.x); xa0[5]=f2bf(w0b.y); xa0[6]=f2bf(w0b.z); xa0[7]=f2bf(w0b.w);
    xa1[0]=f2bf(w1a.x); xa1[1]=f2bf(w1a.y); xa1[2]=f2bf(w1a.z); xa1[3]=f2bf(w1a.w);
    xa1[4]=f2bf(w1b.x); xa1[5]=f2bf(w1b.y); xa1[6]=f2bf(w1b.z); xa1[7]=f2bf(w1b.w);

    float* myl = lds[wv];
#pragma unroll
    for (int t = 0; t < TPW; ++t) {
        long jt = j0 + t * 32;
        const float4* bp = reinterpret_cast<const float4*>(pv + (jt + n) * KDIM + kh * 8);
        float4 ba = bp[0], bb = bp[1];
        bf16x8 yf;
        yf[0]=f2bf(ba.x); yf[1]=f2bf(ba.y); yf[2]=f2bf(ba.z); yf[3]=f2bf(ba.w);
        yf[4]=f2bf(bb.x); yf[5]=f2bf(bb.y); yf[6]=f2bf(bb.z); yf[7]=f2bf(bb.w);

        f32x16 acc0 = {0,0,0,0, 0,0,0,0, 0,0,0,0, 0,0,0,0};
        f32x16 acc1 = {0,0,0,0, 0,0,0,0, 0,0,0,0, 0,0,0,0};
        acc0 = __builtin_amdgcn_mfma_f32_32x32x16_bf16(xa0, yf, acc0, 0, 0, 0);
        acc1 = __builtin_amdgcn_mfma_f32_32x32x16_bf16(xa1, yf, acc1, 0, 0, 0);
#pragma unroll
        for (int q = 0; q < 4; ++q) {
            vfloat4 s0 = {acc0[4*q], acc0[4*q+1], acc0[4*q+2], acc0[4*q+3]};
            vfloat4 s1 = {acc1[4*q], acc1[4*q+1], acc1[4*q+2], acc1[4*q+3]};
            *reinterpret_cast<vfloat4*>(myl + n * LSTR + 8*q + 4*kh)      = s0;
            *reinterpret_cast<vfloat4*>(myl + n * LSTR + 32 + 8*q + 4*kh) = s1;
        }
#pragma unroll
        for (int i = 0; i < 8; ++i) {
            int row  = 4*i + (l >> 4);
            int colf = (l & 15) * 4;
            vfloat4 v = *reinterpret_cast<const vfloat4*>(myl + row * LSTR + colf);
            *reinterpret_cast<vfloat4*>(outv + (jt + row) * DDIM + colf) = v;
        }
    }
}

__global__ __launch_bounds__(256) void fill_idx_plain(float* __restrict__ out) {
    int gid = blockIdx.x * 256 + threadIdx.x;
    int j0 = gid << 2;
    vfloat4 rv, cv;
#pragma unroll
    for (int i = 0; i < 4; ++i) {
        int j = j0 + i;
        int g = j >> 12;
        int rem = j & 4095;
        rv[i] = (float)((g << 6) + (rem >> 6));
        cv[i] = (float)((g << 6) + (rem & 63));
    }
    *reinterpret_cast<vfloat4*>(out + j0)      = rv;
    *reinterpret_cast<vfloat4*>(out + EF + j0) = cv;
}

__global__ __launch_bounds__(256) void scatter_edges(const float* __restrict__ ea,
                                                     const int* __restrict__ ei,
                                                     float* __restrict__ outv) {
    int gid = blockIdx.x * 256 + threadIdx.x;
    int e = gid >> 4;
    int t = gid & 15;
    long slot = edge_slot(ei, e);
    float4 v = *reinterpret_cast<const float4*>(ea + (long)e * DDIM + t * 4);
    float* dst = outv + slot * DDIM + t * 4;
    unsafeAtomicAdd(dst + 0, v.x);
    unsafeAtomicAdd(dst + 1, v.y);
    unsafeAtomicAdd(dst + 2, v.z);
    unsafeAtomicAdd(dst + 3, v.w);
}

extern "C" void kernel_launch(void* const* d_in, const int* in_sizes, int n_in,
                              void* d_out, int out_size, void* d_ws, size_t ws_size,
                              hipStream_t stream) {
    const float* poly_val  = (const float*)d_in[0];
    const float* edge_attr = (const float*)d_in[1];
    const float* W         = (const float*)d_in[2];
    const int*   edge_index = (const int*)d_in[4];

    float* out  = (float*)d_out;
    float* outv = out + 2 * (long)EF;

    if (ws_size >= (size_t)WS_NEED) {
        char* ws = (char*)d_ws;
        unsigned* cnt  = (unsigned*)(ws + WS_CNT_OFF);
        int*      list = (int*)     (ws + WS_LIST_OFF);
        unsigned* ovfc = (unsigned*)(ws + WS_OVFC_OFF);
        int*      ovfl = (int*)     (ws + WS_OVFL_OFF);

        fill_idx<<<EF / 4 / 256, 256, 0, stream>>>(out, cnt, ovfc);
        bin_edges<<<NEDGE / 256, 256, 0, stream>>>(edge_index, cnt, list, ovfc, ovfl);
        pv_fused<<<PVBLK, 256, 0, stream>>>(poly_val, W, edge_attr, cnt, list, outv);
        ovf_fix<<<4, 256, 0, stream>>>(edge_attr, edge_index, ovfc, ovfl, outv);
    } else {
        fill_idx_plain<<<EF / 4 / 256, 256, 0, stream>>>(out);
        pv_gemm<<<PVBLK, 256, 0, stream>>>(poly_val, W, outv);
        scatter_edges<<<(NEDGE * 16) / 256, 256, 0, stream>>>(edge_attr, edge_index, outv);
    }
}

// Round 19
// 45.182 us; speedup vs baseline: 5.6863x; 1.0052x over previous
//
#include <hip/hip_runtime.h>

// Problem constants: B=128, n=64, E=65536, K=16, D=64, e_full=524288
#define EF      524288
#define NEDGE   65536
#define KDIM    16
#define DDIM    64
#define TPW     2
#define PVBLK   (EF / (32 * TPW) / 4)   // 2048 blocks, 4 waves each
#define LSTR    68
#define NTILE   (EF / 32)               // 16384 slot-tiles of 32 rows
#define CAP     64                      // edge-list capacity per tile (avg 4)
#define PF      8                       // edge rows prefetched into registers

typedef float vfloat4 __attribute__((ext_vector_type(4)));
typedef short bf16x8  __attribute__((ext_vector_type(8)));
typedef float f32x16  __attribute__((ext_vector_type(16)));

__device__ __forceinline__ short f2bf(float f) {   // f32 -> bf16, RNE
    unsigned u = __float_as_uint(f);
    return (short)((u + 0x7FFFu + ((u >> 16) & 1u)) >> 16);
}

__device__ __forceinline__ long edge_slot(const int* ei, int e) {
    int r = ei[e];
    int c = ei[NEDGE + e];
    return ((long)(r >> 6) << 12) + ((long)(r & 63) << 6) + (long)(c & 63);
}

// ws layout: [0,64K) tile counts | [64K,64K+4M) lists | ovf_cnt | ovf list
#define WS_CNT_OFF   0
#define WS_LIST_OFF  (64 * 1024)
#define WS_OVFC_OFF  (WS_LIST_OFF + NTILE * CAP * 4)
#define WS_OVFL_OFF  (WS_OVFC_OFF + 4)
#define WS_NEED      (WS_OVFL_OFF + NEDGE * 4)

// ---------------------------------------------------------------------------
// zero_cnt: clear tile counters + overflow counter (idx fill moved into
// pv_fused -- R13 showed gaps~0, so serial fill time was pure cost).
// ---------------------------------------------------------------------------
__global__ __launch_bounds__(256) void zero_cnt(unsigned* __restrict__ cnt,
                                                unsigned* __restrict__ ovfc) {
    int gid = blockIdx.x * 256 + threadIdx.x;   // 16384 threads
    cnt[gid] = 0u;
    if (gid == 0) *ovfc = 0u;
}

// ---------------------------------------------------------------------------
// bin_edges: append (e<<5 | row_local) to the slot-tile's list.
// ---------------------------------------------------------------------------
__global__ __launch_bounds__(256) void bin_edges(const int* __restrict__ ei,
                                                 unsigned* __restrict__ cnt,
                                                 int* __restrict__ list,
                                                 unsigned* __restrict__ ovfc,
                                                 int* __restrict__ ovfl) {
    int e = blockIdx.x * 256 + threadIdx.x;     // NEDGE threads
    long slot = edge_slot(ei, e);
    int tile = (int)(slot >> 5);
    int row  = (int)(slot & 31);
    unsigned pos = atomicAdd(&cnt[tile], 1u);
    if (pos < CAP) list[tile * CAP + pos] = (e << 5) | row;
    else           ovfl[atomicAdd(ovfc, 1u)] = e;
}

// ---------------------------------------------------------------------------
// pv_fused v5:
//  * ea prefetch UNCONDITIONAL with clamped edge index ((u>>5)&65535) --
//    breaks the cnt->ea dependence; prologue = cnt || (list->ea) || pv || W.
//    Garbage entries past ec load in-bounds junk that is never consumed.
//  * idx-fill folded in: each block writes its 512 contiguous out floats
//    in the latency shadow between load-issue and MFMA.
// ---------------------------------------------------------------------------
__global__ __launch_bounds__(256) void pv_fused(const float* __restrict__ pv,
                                                const float* __restrict__ W,
                                                const float* __restrict__ ea,
                                                const unsigned* __restrict__ cnt,
                                                const int* __restrict__ list,
                                                float* __restrict__ out,
                                                float* __restrict__ outv) {
    __shared__ float lds[4][32 * LSTR];
    int tid = threadIdx.x;
    int wv  = tid >> 6;
    int l   = tid & 63;
    int n   = l & 31;
    int kh  = l >> 5;
    long j0 = ((long)blockIdx.x * 4 + wv) * (32 * TPW);
    int tile0 = (int)(j0 >> 5);

    // ---- issue-early: cnt (2), list (16, unconditional) ----
    unsigned ec0 = cnt[tile0];
    unsigned ec1 = cnt[tile0 + 1];
    int pk0[PF], pk1[PF];
#pragma unroll
    for (int i = 0; i < PF; ++i) {
        pk0[i] = list[(long)tile0 * CAP + i];
        pk1[i] = list[(long)(tile0 + 1) * CAP + i];
    }

    // ---- idx fill for this block's 256 rows (independent; hides latency) ----
    {
        int j = blockIdx.x * 256 + tid;         // [0, EF)
        int g = j >> 12;
        int rem = j & 4095;
        out[j]      = (float)((g << 6) + (rem >> 6));
        out[EF + j] = (float)((g << 6) + (rem & 63));
    }

    // ---- ea rows: unconditional, index clamped in-bounds ----
    float vpre0[PF], vpre1[PF];
#pragma unroll
    for (int i = 0; i < PF; ++i) {
        unsigned e0 = ((unsigned)pk0[i] >> 5) & (NEDGE - 1);
        unsigned e1 = ((unsigned)pk1[i] >> 5) & (NEDGE - 1);
        vpre0[i] = ea[(long)e0 * DDIM + l];
        vpre1[i] = ea[(long)e1 * DDIM + l];
    }

    if (ec0 > CAP) ec0 = CAP;
    if (ec1 > CAP) ec1 = CAP;
    unsigned ep0 = ec0 > PF ? PF : ec0;
    unsigned ep1 = ec1 > PF ? PF : ec1;

    // ---- pv fragments (both tiles) ----
    const float4* bp0 = reinterpret_cast<const float4*>(pv + (j0 + n) * KDIM + kh * 8);
    const float4* bp1 = reinterpret_cast<const float4*>(pv + (j0 + 32 + n) * KDIM + kh * 8);
    float4 ba0 = bp0[0], bb0 = bp0[1], ba1 = bp1[0], bb1 = bp1[1];

    // ---- W fragments (L1-resident) ----
    const float4* wp0 = reinterpret_cast<const float4*>(W + n * KDIM + kh * 8);
    const float4* wp1 = reinterpret_cast<const float4*>(W + (32 + n) * KDIM + kh * 8);
    float4 w0a = wp0[0], w0b = wp0[1], w1a = wp1[0], w1b = wp1[1];
    bf16x8 xa0, xa1;
    xa0[0]=f2bf(w0a.x); xa0[1]=f2bf(w0a.y); xa0[2]=f2bf(w0a.z); xa0[3]=f2bf(w0a.w);
    xa0[4]=f2bf(w0b.x); xa0[5]=f2bf(w0b.y); xa0[6]=f2bf(w0b.z); xa0[7]=f2bf(w0b.w);
    xa1[0]=f2bf(w1a.x); xa1[1]=f2bf(w1a.y); xa1[2]=f2bf(w1a.z); xa1[3]=f2bf(w1a.w);
    xa1[4]=f2bf(w1b.x); xa1[5]=f2bf(w1b.y); xa1[6]=f2bf(w1b.z); xa1[7]=f2bf(w1b.w);

    float* myl = lds[wv];

    // ================= tile 0 =================
    {
        bf16x8 yf;
        yf[0]=f2bf(ba0.x); yf[1]=f2bf(ba0.y); yf[2]=f2bf(ba0.z); yf[3]=f2bf(ba0.w);
        yf[4]=f2bf(bb0.x); yf[5]=f2bf(bb0.y); yf[6]=f2bf(bb0.z); yf[7]=f2bf(bb0.w);
        f32x16 acc0 = {0,0,0,0, 0,0,0,0, 0,0,0,0, 0,0,0,0};
        f32x16 acc1 = {0,0,0,0, 0,0,0,0, 0,0,0,0, 0,0,0,0};
        acc0 = __builtin_amdgcn_mfma_f32_32x32x16_bf16(xa0, yf, acc0, 0, 0, 0);
        acc1 = __builtin_amdgcn_mfma_f32_32x32x16_bf16(xa1, yf, acc1, 0, 0, 0);
#pragma unroll
        for (int q = 0; q < 4; ++q) {
            vfloat4 s0 = {acc0[4*q], acc0[4*q+1], acc0[4*q+2], acc0[4*q+3]};
            vfloat4 s1 = {acc1[4*q], acc1[4*q+1], acc1[4*q+2], acc1[4*q+3]};
            *reinterpret_cast<vfloat4*>(myl + n * LSTR + 8*q + 4*kh)      = s0;
            *reinterpret_cast<vfloat4*>(myl + n * LSTR + 32 + 8*q + 4*kh) = s1;
        }
#pragma unroll
        for (int i = 0; i < PF; ++i)
            if ((unsigned)i < ep0) myl[(pk0[i] & 31) * LSTR + l] += vpre0[i];
        for (unsigned i = PF; i < ec0; ++i) {     // rare tail
            int packed = list[(long)tile0 * CAP + i];
            myl[(packed & 31) * LSTR + l] += ea[(long)(packed >> 5) * DDIM + l];
        }
#pragma unroll
        for (int i = 0; i < 8; ++i) {
            int row  = 4*i + (l >> 4);
            int colf = (l & 15) * 4;
            vfloat4 v = *reinterpret_cast<const vfloat4*>(myl + row * LSTR + colf);
            *reinterpret_cast<vfloat4*>(outv + (j0 + row) * DDIM + colf) = v;
        }
    }

    // ================= tile 1 =================
    {
        bf16x8 yf;
        yf[0]=f2bf(ba1.x); yf[1]=f2bf(ba1.y); yf[2]=f2bf(ba1.z); yf[3]=f2bf(ba1.w);
        yf[4]=f2bf(bb1.x); yf[5]=f2bf(bb1.y); yf[6]=f2bf(bb1.z); yf[7]=f2bf(bb1.w);
        f32x16 acc0 = {0,0,0,0, 0,0,0,0, 0,0,0,0, 0,0,0,0};
        f32x16 acc1 = {0,0,0,0, 0,0,0,0, 0,0,0,0, 0,0,0,0};
        acc0 = __builtin_amdgcn_mfma_f32_32x32x16_bf16(xa0, yf, acc0, 0, 0, 0);
        acc1 = __builtin_amdgcn_mfma_f32_32x32x16_bf16(xa1, yf, acc1, 0, 0, 0);
#pragma unroll
        for (int q = 0; q < 4; ++q) {
            vfloat4 s0 = {acc0[4*q], acc0[4*q+1], acc0[4*q+2], acc0[4*q+3]};
            vfloat4 s1 = {acc1[4*q], acc1[4*q+1], acc1[4*q+2], acc1[4*q+3]};
            *reinterpret_cast<vfloat4*>(myl + n * LSTR + 8*q + 4*kh)      = s0;
            *reinterpret_cast<vfloat4*>(myl + n * LSTR + 32 + 8*q + 4*kh) = s1;
        }
#pragma unroll
        for (int i = 0; i < PF; ++i)
            if ((unsigned)i < ep1) myl[(pk1[i] & 31) * LSTR + l] += vpre1[i];
        for (unsigned i = PF; i < ec1; ++i) {     // rare tail
            int packed = list[(long)(tile0 + 1) * CAP + i];
            myl[(packed & 31) * LSTR + l] += ea[(long)(packed >> 5) * DDIM + l];
        }
#pragma unroll
        for (int i = 0; i < 8; ++i) {
            int row  = 4*i + (l >> 4);
            int colf = (l & 15) * 4;
            vfloat4 v = *reinterpret_cast<const vfloat4*>(myl + row * LSTR + colf);
            *reinterpret_cast<vfloat4*>(outv + (j0 + 32 + row) * DDIM + colf) = v;
        }
    }
}

// ---------------------------------------------------------------------------
// ovf_fix: atomic-add any overflow edges (statistically none; insurance).
// ---------------------------------------------------------------------------
__global__ __launch_bounds__(256) void ovf_fix(const float* __restrict__ ea,
                                               const int* __restrict__ ei,
                                               const unsigned* __restrict__ ovfc,
                                               const int* __restrict__ ovfl,
                                               float* __restrict__ outv) {
    unsigned nov = *ovfc;
    for (unsigned i = blockIdx.x * 256 + threadIdx.x; i < nov; i += 4 * 256) {
        int e = ovfl[i];
        long slot = edge_slot(ei, e);
        float* dst = outv + slot * DDIM;
        const float* src = ea + (long)e * DDIM;
        for (int j = 0; j < DDIM; ++j) unsafeAtomicAdd(dst + j, src[j]);
    }
}

// ---------------------------------------------------------------------------
// Fallback: proven separate path when ws too small.
// ---------------------------------------------------------------------------
__global__ __launch_bounds__(256) void pv_gemm(const float* __restrict__ pv,
                                               const float* __restrict__ W,
                                               float* __restrict__ outv) {
    __shared__ float lds[4][32 * LSTR];
    int tid = threadIdx.x;
    int wv  = tid >> 6;
    int l   = tid & 63;
    int n   = l & 31;
    int kh  = l >> 5;
    long j0 = ((long)blockIdx.x * 4 + wv) * (32 * TPW);

    const float4* wp0 = reinterpret_cast<const float4*>(W + n * KDIM + kh * 8);
    const float4* wp1 = reinterpret_cast<const float4*>(W + (32 + n) * KDIM + kh * 8);
    float4 w0a = wp0[0], w0b = wp0[1], w1a = wp1[0], w1b = wp1[1];
    bf16x8 xa0, xa1;
    xa0[0]=f2bf(w0a.x); xa0[1]=f2bf(w0a.y); xa0[2]=f2bf(w0a.z); xa0[3]=f2bf(w0a.w);
    xa0[4]=f2bf(w0b.x); xa0[5]=f2bf(w0b.y); xa0[6]=f2bf(w0b.z); xa0[7]=f2bf(w0b.w);
    xa1[0]=f2bf(w1a.x); xa1[1]=f2bf(w1a.y); xa1[2]=f2bf(w1a.z); xa1[3]=f2bf(w1a.w);
    xa1[4]=f2bf(w1b.x); xa1[5]=f2bf(w1b.y); xa1[6]=f2bf(w1b.z); xa1[7]=f2bf(w1b.w);

    float* myl = lds[wv];
#pragma unroll
    for (int t = 0; t < TPW; ++t) {
        long jt = j0 + t * 32;
        const float4* bp = reinterpret_cast<const float4*>(pv + (jt + n) * KDIM + kh * 8);
        float4 ba = bp[0], bb = bp[1];
        bf16x8 yf;
        yf[0]=f2bf(ba.x); yf[1]=f2bf(ba.y); yf[2]=f2bf(ba.z); yf[3]=f2bf(ba.w);
        yf[4]=f2bf(bb.x); yf[5]=f2bf(bb.y); yf[6]=f2bf(bb.z); yf[7]=f2bf(bb.w);

        f32x16 acc0 = {0,0,0,0, 0,0,0,0, 0,0,0,0, 0,0,0,0};
        f32x16 acc1 = {0,0,0,0, 0,0,0,0, 0,0,0,0, 0,0,0,0};
        acc0 = __builtin_amdgcn_mfma_f32_32x32x16_bf16(xa0, yf, acc0, 0, 0, 0);
        acc1 = __builtin_amdgcn_mfma_f32_32x32x16_bf16(xa1, yf, acc1, 0, 0, 0);
#pragma unroll
        for (int q = 0; q < 4; ++q) {
            vfloat4 s0 = {acc0[4*q], acc0[4*q+1], acc0[4*q+2], acc0[4*q+3]};
            vfloat4 s1 = {acc1[4*q], acc1[4*q+1], acc1[4*q+2], acc1[4*q+3]};
            *reinterpret_cast<vfloat4*>(myl + n * LSTR + 8*q + 4*kh)      = s0;
            *reinterpret_cast<vfloat4*>(myl + n * LSTR + 32 + 8*q + 4*kh) = s1;
        }
#pragma unroll
        for (int i = 0; i < 8; ++i) {
            int row  = 4*i + (l >> 4);
            int colf = (l & 15) * 4;
            vfloat4 v = *reinterpret_cast<const vfloat4*>(myl + row * LSTR + colf);
            *reinterpret_cast<vfloat4*>(outv + (jt + row) * DDIM + colf) = v;
        }
    }
}

__global__ __launch_bounds__(256) void fill_idx_plain(float* __restrict__ out) {
    int gid = blockIdx.x * 256 + threadIdx.x;
    int j0 = gid << 2;
    vfloat4 rv, cv;
#pragma unroll
    for (int i = 0; i < 4; ++i) {
        int j = j0 + i;
        int g = j >> 12;
        int rem = j & 4095;
        rv[i] = (float)((g << 6) + (rem >> 6));
        cv[i] = (float)((g << 6) + (rem & 63));
    }
    *reinterpret_cast<vfloat4*>(out + j0)      = rv;
    *reinterpret_cast<vfloat4*>(out + EF + j0) = cv;
}

__global__ __launch_bounds__(256) void scatter_edges(const float* __restrict__ ea,
                                                     const int* __restrict__ ei,
                                                     float* __restrict__ outv) {
    int gid = blockIdx.x * 256 + threadIdx.x;
    int e = gid >> 4;
    int t = gid & 15;
    long slot = edge_slot(ei, e);
    float4 v = *reinterpret_cast<const float4*>(ea + (long)e * DDIM + t * 4);
    float* dst = outv + slot * DDIM + t * 4;
    unsafeAtomicAdd(dst + 0, v.x);
    unsafeAtomicAdd(dst + 1, v.y);
    unsafeAtomicAdd(dst + 2, v.z);
    unsafeAtomicAdd(dst + 3, v.w);
}

extern "C" void kernel_launch(void* const* d_in, const int* in_sizes, int n_in,
                              void* d_out, int out_size, void* d_ws, size_t ws_size,
                              hipStream_t stream) {
    const float* poly_val  = (const float*)d_in[0];
    const float* edge_attr = (const float*)d_in[1];
    const float* W         = (const float*)d_in[2];
    const int*   edge_index = (const int*)d_in[4];

    float* out  = (float*)d_out;
    float* outv = out + 2 * (long)EF;

    if (ws_size >= (size_t)WS_NEED) {
        char* ws = (char*)d_ws;
        unsigned* cnt  = (unsigned*)(ws + WS_CNT_OFF);
        int*      list = (int*)     (ws + WS_LIST_OFF);
        unsigned* ovfc = (unsigned*)(ws + WS_OVFC_OFF);
        int*      ovfl = (int*)     (ws + WS_OVFL_OFF);

        zero_cnt<<<NTILE / 256, 256, 0, stream>>>(cnt, ovfc);
        bin_edges<<<NEDGE / 256, 256, 0, stream>>>(edge_index, cnt, list, ovfc, ovfl);
        pv_fused<<<PVBLK, 256, 0, stream>>>(poly_val, W, edge_attr, cnt, list, out, outv);
        ovf_fix<<<4, 256, 0, stream>>>(edge_attr, edge_index, ovfc, ovfl, outv);
    } else {
        fill_idx_plain<<<EF / 4 / 256, 256, 0, stream>>>(out);
        pv_gemm<<<PVBLK, 256, 0, stream>>>(poly_val, W, outv);
        scatter_edges<<<(NEDGE * 16) / 256, 256, 0, stream>>>(edge_attr, edge_index, outv);
    }
}